// Round 7
// baseline (242.704 us; speedup 1.0000x reference)
//
#include <hip/hip_runtime.h>
#include <cstdint>
#include <cstddef>

// ---------------- constants ----------------
constexpr int B_   = 4096;
constexpr int DIN  = 256;
constexpr int OUT_ = 32;
constexpr int MM   = 128;
constexpr int NH_  = 2;
constexpr int HO   = 64;          // NH*OUT
constexpr int TRIL = 8256;        // 128*129/2
constexpr float JIT = 1e-4f;

// ---------------- workspace layout ----------------
constexpr size_t al4k(size_t x){ return (x + 4095) & ~size_t(4095); }
constexpr size_t OFF_FLAG  = 0;                               // int
constexpr size_t OFF_INVLS = 4096;                            // f32 [2][256]
constexpr size_t OFF_SF2   = al4k(OFF_INVLS + 2*256*4);       // f32 [2]
constexpr size_t OFF_ZN2   = al4k(OFF_SF2 + 64);              // f32 [2][4096]
constexpr size_t OFF_XN2   = al4k(OFF_ZN2 + 8192*4);          // f32 [2][4096]
constexpr size_t OFF_W     = al4k(OFF_XN2 + 8192*4);          // f32 [64][128]
constexpr size_t OFF_ZS    = al4k(OFF_W + 8192*4);            // bf16 [2][4096][256]
constexpr size_t OFF_XS    = al4k(OFF_ZS + (size_t)2097152*2);
constexpr size_t OFF_VTH   = al4k(OFF_XS + (size_t)2097152*2); // (unused after merge)
constexpr size_t OFF_VTL   = al4k(OFF_VTH + (size_t)1048576*2);
constexpr size_t OFF_CHI   = al4k(OFF_VTL + (size_t)1048576*2);// bf16 [64][128][128]
constexpr size_t OFF_CLO   = al4k(OFF_CHI + (size_t)1048576*2);

typedef float f32x4 __attribute__((ext_vector_type(4)));
typedef short short8 __attribute__((ext_vector_type(8)));

__device__ __forceinline__ float bf2f(unsigned short u){
  union{unsigned int i; float f;} v; v.i = ((unsigned)u) << 16; return v.f;
}
__device__ __forceinline__ unsigned short f2bf(float f){
  union{float f; unsigned int i;} v; v.f = f;
  unsigned int r = v.i + 0x7fffu + ((v.i >> 16) & 1u);
  return (unsigned short)(r >> 16);
}
__device__ __forceinline__ float ldin(const void* p, size_t i, int isbf){
  if (isbf) return bf2f(((const unsigned short*)p)[i]);
  return ((const float*)p)[i];
}
__device__ __forceinline__ void stout(void* p, size_t i, float v, int isbf){
  if (isbf) ((unsigned short*)p)[i] = f2bf(v);
  else ((float*)p)[i] = v;
}
// async global->LDS, 16B per lane; LDS dest = wave-uniform base + lane*16
__device__ __forceinline__ void gl_lds16(const unsigned short* g, unsigned short* l){
  __builtin_amdgcn_global_load_lds(
      (const __attribute__((address_space(1))) unsigned int*)g,
      (__attribute__((address_space(3))) unsigned int*)l, 16, 0, 0);
}

// ---------------- K1: detect dtype + hypers (merged) ----------------
__global__ void k_hypers(const void* __restrict__ theta, const void* __restrict__ x,
                         int* __restrict__ flagp,
                         float* __restrict__ inv_ls, float* __restrict__ sf2){
  __shared__ int sflag;
  int t = threadIdx.x;
  if (t < 64){
    unsigned int w0 = ((const unsigned int*)theta)[t];
    unsigned int w1 = ((const unsigned int*)x)[t];
    float a0 = fabsf(bf2f((unsigned short)(w0 & 0xffffu)));
    float a1 = fabsf(bf2f((unsigned short)(w1 & 0xffffu)));
    int c = ((a0 > 9.3e-10f && a0 < 64.f) ? 1 : 0) + ((a1 > 9.3e-10f && a1 < 64.f) ? 1 : 0);
    c += __shfl_down(c, 32); c += __shfl_down(c, 16); c += __shfl_down(c, 8);
    c += __shfl_down(c, 4);  c += __shfl_down(c, 2);  c += __shfl_down(c, 1);
    if (t == 0){ sflag = (c >= 64) ? 1 : 0; *flagp = sflag; }
  }
  __syncthreads();
  const int isbf = sflag;
  for (int i = t; i < NH_*257; i += blockDim.x){
    int h = i / 257, j = i - h*257;
    float v = ldin(theta, i, isbf);
    if (j == 0) sf2[h] = __expf(v);
    else inv_ls[h*DIN + j - 1] = __expf(-v);
  }
}

// ---------------- K2: scale x and z by 1/ls -> bf16 + squared norms --------
__global__ void k_scale(const void* __restrict__ xsrc, const void* __restrict__ zsrc,
                        const int* flagp, const float* __restrict__ inv_ls,
                        unsigned short* __restrict__ xdst, unsigned short* __restrict__ zdst,
                        float* __restrict__ xn2, float* __restrict__ zn2){
  const int isbf = *flagp;
  const int wave = threadIdx.x >> 6, lane = threadIdx.x & 63;
  int bx = blockIdx.x;
  const void* src; unsigned short* dst; float* n2; int r;
  if (bx < 1024){ src = xsrc; dst = xdst; n2 = xn2; r = bx*4 + wave; }
  else          { src = zsrc; dst = zdst; n2 = zn2; r = (bx-1024)*4 + wave; }
  const int d0 = lane*4;
  float v[4];
  if (isbf){
    uint2 uu = *(const uint2*)((const unsigned short*)src + (size_t)r*DIN + d0);
    v[0]=bf2f((unsigned short)(uu.x & 0xffffu)); v[1]=bf2f((unsigned short)(uu.x >> 16));
    v[2]=bf2f((unsigned short)(uu.y & 0xffffu)); v[3]=bf2f((unsigned short)(uu.y >> 16));
  } else {
    f32x4 f = *(const f32x4*)((const float*)src + (size_t)r*DIN + d0);
    v[0]=f[0]; v[1]=f[1]; v[2]=f[2]; v[3]=f[3];
  }
  #pragma unroll
  for (int h = 0; h < 2; ++h){
    f32x4 il = *(const f32x4*)(inv_ls + h*DIN + d0);
    unsigned short rb[4];
    float p = 0.f;
    #pragma unroll
    for (int k = 0; k < 4; ++k){
      float s = v[k] * il[k];
      rb[k] = f2bf(s);
      float qv = bf2f(rb[k]);
      p += qv*qv;
    }
    uint2 pk;
    pk.x = (unsigned)rb[0] | ((unsigned)rb[1] << 16);
    pk.y = (unsigned)rb[2] | ((unsigned)rb[3] << 16);
    *(uint2*)(dst + ((size_t)h*4096 + r)*DIN + d0) = pk;
    p += __shfl_xor(p, 32); p += __shfl_xor(p, 16); p += __shfl_xor(p, 8);
    p += __shfl_xor(p, 4);  p += __shfl_xor(p, 2);  p += __shfl_xor(p, 1);
    if (lane == 0) n2[(size_t)h*4096 + r] = p;
  }
}

// ---------------- K3: FUSED kuu + lookahead-Cholesky + trtri + Q/w/P/C -------------
// 512 threads / 8 waves. LDS regions (153 KB total):
//   A [0..82432):      float T tiles (80.5KB) + zn2l; later aliased by Sth/Stl
//   B [82432..152064): kuu z-staging bufs (3x8KB), then VT hi/lo, then Qh/Ql, Ph/Pl
//   floats [152064..): ul[128], wpart[8][128]
// Lookahead: after solve(kb), wave7 updates diag tile (kb+1,kb+1); then wave0
// factors panel(kb+1) CONCURRENTLY with waves1-7 doing the remaining update tiles.
constexpr int TLD = 20;          // tile leading dim (floats)
constexpr int TSZ = 16*TLD;      // 320 floats per tile
__device__ __forceinline__ int tb(int bi, int bj){ return (bi*(bi+1)/2 + bj)*TSZ; }
__device__ __forceinline__ int vb(int bi, int bj){ return (36 + bi*(bi-1)/2 + bj)*TSZ; }
__device__ __forceinline__ int tri_bi(int t){
  int bi = (int)((sqrtf(8.f*t + 1.f) - 1.f) * 0.5f);
  while ((bi+1)*(bi+2)/2 <= t) ++bi;
  while (bi*(bi+1)/2 > t) --bi;
  return bi;
}

__global__ __launch_bounds__(512) void k_fact(
    const unsigned short* __restrict__ zs, const float* __restrict__ zn2,
    const float* __restrict__ sf2,
    const void* __restrict__ u_mean, const void* __restrict__ u_tril,
    const int* flagp, float* __restrict__ wg,
    unsigned short* __restrict__ Chi, unsigned short* __restrict__ Clo){
  const int ho = blockIdx.x, h = ho >> 5, o = ho & 31;
  const int tid = threadIdx.x;
  const int lane = tid & 63, wid = tid >> 6;      // 8 waves
  const int l15 = lane & 15, q = lane >> 4;
  const int wn = wid * 16;                        // 16 output-cols per wave
  const int isbf = *flagp;
  extern __shared__ char smem[];
  float* T = (float*)smem;                            // 64 tiles
  float* zn2l = T + 64*TSZ;                           // [128] @81920
  unsigned short* VTh = (unsigned short*)(smem + 82432);   // [128][136]
  unsigned short* VTl = (unsigned short*)(smem + 117248);  // [128][136]
  unsigned short* Sth = (unsigned short*)smem;             // alias A (post-trtri)
  unsigned short* Stl = (unsigned short*)(smem + 34816);
  unsigned short* Qh = VTh;                                // alias B (post-Q-phase)
  unsigned short* Ql = VTl;
  float* ul    = (float*)(smem + 152064);             // [128]
  float* wpart = (float*)(smem + 152576);             // [8][128]
  // kuu z-staging triple buffer, aliases region B (dead until VT conversion)
  unsigned short* zbB0 = (unsigned short*)(smem + 82432);
  unsigned short* zbB1 = (unsigned short*)(smem + 90624);
  unsigned short* zbB2 = (unsigned short*)(smem + 98816);
  unsigned short* zbB[3] = { zbB0, zbB1, zbB2 };

  if (tid < 128){
    zn2l[tid] = zn2[ho*128 + tid];
    ul[tid]   = ldin(u_mean, (size_t)o*128 + tid, isbf);
  }
  const size_t zbase = (size_t)ho * 32768;
  const int sw = ((q ^ ((l15 >> 1) & 3)) << 3);
  const int rA = wn + (lane >> 2);
  const int sg = ((lane & 3) ^ ((rA >> 1) & 3)) << 3;
  const f32x4 z4 = {0.f,0.f,0.f,0.f};

  auto STAGEZ = [&](int c, unsigned short* zd){
    gl_lds16(zs + zbase + (size_t)rA*256 + c*32 + sg, zd + wn*32);
  };

  // ---- phase kuu: zs zs^T via MFMA, 3-buffer counted-vmcnt pipeline ----
  f32x4 acck[8];
  #pragma unroll
  for (int mt=0; mt<8; ++mt) acck[mt]=z4;
  STAGEZ(0, zbB0);
  STAGEZ(1, zbB1);
  __syncthreads();   // full drain: zn2l/ul + stages 0,1 landed; LDS visible
  #pragma unroll
  for (int kc = 0; kc < 8; ++kc){
    unsigned short* zc = zbB[kc % 3];
    if (kc + 2 < 8) STAGEZ(kc + 2, zbB[(kc + 2) % 3]);
    // per-wave loads: 1 per STAGEZ; in flight <= chunks kc+1, kc+2
    if (kc < 6)       asm volatile("s_waitcnt vmcnt(2)" ::: "memory");
    else if (kc == 6) asm volatile("s_waitcnt vmcnt(1)" ::: "memory");
    else              asm volatile("s_waitcnt vmcnt(0)" ::: "memory");
    __builtin_amdgcn_s_barrier();           // all waves' chunk-kc landed
    __builtin_amdgcn_sched_barrier(0);
    short8 b0 = *(const short8*)(zc + (wn + l15)*32 + sw);
    #pragma unroll
    for (int mt=0; mt<8; ++mt){
      short8 a = *(const short8*)(zc + (mt*16 + l15)*32 + sw);
      acck[mt] = __builtin_amdgcn_mfma_f32_16x16x32_bf16(a, b0, acck[mt], 0,0,0);
    }
    asm volatile("s_waitcnt lgkmcnt(0)" ::: "memory");
    __builtin_amdgcn_sched_barrier(0);
    __builtin_amdgcn_s_barrier();           // reads done before buf reuse
  }
  // ---- epilogue: kuu -> T tiles (lower + full diag), + jitter ----
  const float s2v = sf2[h];
  {
    const int n = wn + l15;
    const float nn = zn2l[n];
    const int bn = wid;
    #pragma unroll
    for (int mt=0; mt<8; ++mt){
      #pragma unroll
      for (int r=0; r<4; ++r){
        int m = mt*16 + q*4 + r;
        float d2 = fmaxf(zn2l[m] + nn - 2.f*acck[mt][r], 0.f);
        float a = s2v * __expf(-0.5f*d2);
        if (m == n) a += JIT;
        int bm = m >> 4;
        if (bn <= bm) T[tb(bm, bn) + (m & 15)*TLD + (n & 15)] = a;
      }
    }
  }
  __syncthreads();
  // ---- lookahead blocked Cholesky, panel width 16 ----
  auto PANEL = [&](int kb){
    float* D = T + tb(kb, kb);
    const int r = lane & 15;
    const bool act = (lane < 16);
    float a[16];
    #pragma unroll
    for (int k = 0; k < 16; ++k) a[k] = 0.f;
    if (act){
      #pragma unroll
      for (int k2 = 0; k2 < 4; ++k2)
        *(f32x4*)(a + 4*k2) = *(const f32x4*)(D + r*TLD + 4*k2);
    }
    #pragma unroll
    for (int c = 0; c < 16; ++c){
      float pr[16];
      #pragma unroll
      for (int k = 0; k < 16; ++k) pr[k] = __shfl(a[k], c);
      float rsq = rsqrtf(pr[c]);
      if (act && r >= c) a[c] *= rsq;
      float lrc = a[c];
      #pragma unroll
      for (int k = 0; k < 16; ++k)
        if (k > c && act && r > c) a[k] -= lrc * (pr[k] * rsq);
    }
    float v[16];
    #pragma unroll
    for (int k = 0; k < 16; ++k) v[k] = 0.f;
    const int c = lane & 15;
    #pragma unroll
    for (int i = 0; i < 16; ++i){
      float lrow[16];
      #pragma unroll
      for (int k = 0; k < 16; ++k) lrow[k] = __shfl(a[k], i);
      float rli = 1.f / lrow[i];
      float s = 0.f;
      #pragma unroll
      for (int k = 0; k < 16; ++k)
        if (k < i) s += ((k >= c) ? lrow[k]*v[k] : 0.f);
      v[i] = (c == i) ? rli : ((c < i) ? -s*rli : 0.f);
    }
    if (act){
      #pragma unroll
      for (int i = 0; i < 16; ++i) D[i*TLD + c] = v[i];
    }
  };
  auto UPDT = [&](int bi, int bj, int kb){
    const int r15 = lane & 15, c0 = (lane >> 4)*4;
    const float* Lr = T + tb(bi, kb) + r15*TLD;
    const float* Lc = T + tb(bj, kb) + c0*TLD;
    float* Cp = T + tb(bi, bj) + r15*TLD + c0;
    float lr[16];
    #pragma unroll
    for (int k2 = 0; k2 < 4; ++k2) *(f32x4*)(lr + 4*k2) = *(const f32x4*)(Lr + 4*k2);
    f32x4 accv = *(const f32x4*)Cp;
    #pragma unroll
    for (int cc = 0; cc < 4; ++cc){
      float lc[16];
      #pragma unroll
      for (int k2 = 0; k2 < 4; ++k2) *(f32x4*)(lc + 4*k2) = *(const f32x4*)(Lc + cc*TLD + 4*k2);
      float s = 0.f;
      #pragma unroll
      for (int k = 0; k < 16; ++k) s += lr[k]*lc[k];
      accv[cc] -= s;
    }
    *(f32x4*)Cp = accv;
  };

  if (wid == 0) PANEL(0);
  __syncthreads();
  for (int kb = 0; kb < 7; ++kb){
    // solve: B(i,kb) <- B(i,kb) * Vd^T for rows below panel kb
    {
      const int gi = kb*16 + 16 + tid;
      if (gi < 128){
        float* Bp = T + tb(gi >> 4, kb) + (gi & 15)*TLD;
        const float* Vd = T + tb(kb, kb);
        float b[16], nb[16];
        #pragma unroll
        for (int k2 = 0; k2 < 4; ++k2) *(f32x4*)(b + 4*k2) = *(const f32x4*)(Bp + 4*k2);
        #pragma unroll
        for (int j = 0; j < 16; ++j){
          float s = 0.f;
          #pragma unroll
          for (int k = 0; k < 16; ++k)
            if (k <= j) s += b[k] * Vd[j*TLD + k];
          nb[j] = s;
        }
        #pragma unroll
        for (int k2 = 0; k2 < 4; ++k2) *(f32x4*)(Bp + 4*k2) = *(const f32x4*)(nb + 4*k2);
      }
    }
    __syncthreads();
    // lookahead step 1: update next diagonal tile only
    if (wid == 7) UPDT(kb+1, kb+1, kb);
    __syncthreads();
    // lookahead step 2: panel(kb+1) on wave0 CONCURRENT with rest of trailing update
    {
      const int D8 = 7 - kb;
      const int Tn = D8*(D8+1)/2;
      if (wid == 0){
        PANEL(kb+1);
      } else {
        for (int tt = wid; tt < Tn; tt += 7){     // tt>=1: diag tile already done
          int bi1 = tri_bi(tt);
          int bj1 = tt - bi1*(bi1+1)/2;
          UPDT(kb+1+bi1, kb+1+bj1, kb);
        }
      }
    }
    __syncthreads();
  }
  // ---- trtri by anti-diagonal wavefronts ----
  {
    const int r15 = lane & 15, c0 = (lane >> 4)*4;
    for (int d = 1; d < 8; ++d){
      for (int tt = wid; tt < 8 - d; tt += 8){
        const int bi = d + tt, jb = bi - d;
        float W0=0.f, W1=0.f, W2=0.f, W3=0.f;
        for (int k = jb; k < bi; ++k){
          const float* Lt = T + tb(bi, k) + r15*TLD;
          const float* Vt = (k == jb) ? (T + tb(jb, jb)) : (T + vb(k, jb));
          float lr[16];
          #pragma unroll
          for (int k2 = 0; k2 < 4; ++k2) *(f32x4*)(lr + 4*k2) = *(const f32x4*)(Lt + 4*k2);
          #pragma unroll
          for (int kk = 0; kk < 16; ++kk){
            f32x4 vv = *(const f32x4*)(Vt + kk*TLD + c0);
            W0 += lr[kk]*vv[0]; W1 += lr[kk]*vv[1];
            W2 += lr[kk]*vv[2]; W3 += lr[kk]*vv[3];
          }
        }
        const float* Vd = T + tb(bi, bi) + r15*TLD;
        const int cgl = (lane >> 4);
        f32x4 Rr = {0.f,0.f,0.f,0.f};
        #pragma unroll
        for (int k = 0; k < 16; ++k){
          float vd = Vd[k];
          float w0 = __shfl(W0, (cgl<<4)|k);
          float w1 = __shfl(W1, (cgl<<4)|k);
          float w2 = __shfl(W2, (cgl<<4)|k);
          float w3 = __shfl(W3, (cgl<<4)|k);
          Rr[0] -= vd*w0; Rr[1] -= vd*w1; Rr[2] -= vd*w2; Rr[3] -= vd*w3;
        }
        *(f32x4*)(T + vb(bi, jb) + r15*TLD + c0) = Rr;
      }
      __syncthreads();
    }
  }
  // ---- convert V (T tiles) -> VT bf16 hi/lo in LDS region B: VT[c][r]=V[r][c] ----
  for (int e = tid; e < 16384; e += 512){
    int c = e >> 7, rr = e & 127;
    int bc = c >> 4, br = rr >> 4;
    float v = 0.f;
    if (br == bc)      v = T[tb(br, bc) + (rr & 15)*TLD + (c & 15)];
    else if (br > bc)  v = T[vb(br, bc) + (rr & 15)*TLD + (c & 15)];
    unsigned short hi = f2bf(v);
    VTh[c*136 + rr] = hi;
    VTl[c*136 + rr] = f2bf(v - bf2f(hi));
  }
  __syncthreads();   // VT complete (and all T reads done -> A free after this phase)
  // ---- phase Q: Q = VT * VT^T via hi/lo 3-pass MFMA, pure LDS reads ----
  f32x4 acc[8];
  #pragma unroll
  for (int mt=0; mt<8; ++mt) acc[mt]=z4;
  #pragma unroll
  for (int kc2 = 0; kc2 < 4; ++kc2){
    const int ko = kc2*32 + q*8;
    short8 b0h = *(const short8*)(VTh + (wn + l15)*136 + ko);
    short8 b0l = *(const short8*)(VTl + (wn + l15)*136 + ko);
    #pragma unroll
    for (int mt=0; mt<8; ++mt){
      short8 ah = *(const short8*)(VTh + (mt*16 + l15)*136 + ko);
      short8 al = *(const short8*)(VTl + (mt*16 + l15)*136 + ko);
      acc[mt] = __builtin_amdgcn_mfma_f32_16x16x32_bf16(ah, b0h, acc[mt], 0,0,0);
      acc[mt] = __builtin_amdgcn_mfma_f32_16x16x32_bf16(ah, b0l, acc[mt], 0,0,0);
      acc[mt] = __builtin_amdgcn_mfma_f32_16x16x32_bf16(al, b0h, acc[mt], 0,0,0);
    }
  }
  // ---- w = Q u (shuffle reduce over the wave's 16 cols) ----
  {
    float u0 = ul[wn + l15];
    float wpm[32];
    #pragma unroll
    for (int mt=0; mt<8; ++mt){
      #pragma unroll
      for (int r=0; r<4; ++r)
        wpm[mt*4+r] = acc[mt][r]*u0;
    }
    #pragma unroll
    for (int i = 0; i < 32; ++i){
      wpm[i] += __shfl_xor(wpm[i], 1);
      wpm[i] += __shfl_xor(wpm[i], 2);
      wpm[i] += __shfl_xor(wpm[i], 4);
      wpm[i] += __shfl_xor(wpm[i], 8);
    }
    if (l15 == 0){
      #pragma unroll
      for (int i = 0; i < 32; ++i){
        int m = (i>>2)*16 + q*4 + (i&3);
        wpart[wid*128 + m] = wpm[i];
      }
    }
  }
  __syncthreads();   // all Q-phase VT reads done (B free to overwrite) + wpart visible
  if (tid < 128){
    float s = 0.f;
    #pragma unroll
    for (int wv = 0; wv < 8; ++wv) s += wpart[wv*128 + tid];
    wg[ho*128 + tid] = s;
  }
  // ---- write Q dense bf16 hi/lo over VT (B); fill St = S^T over T (A) ----
  {
    const int n0 = wn + l15;
    #pragma unroll
    for (int mt=0; mt<8; ++mt){
      #pragma unroll
      for (int r=0; r<4; ++r){
        int m = mt*16 + q*4 + r;
        float v0 = acc[mt][r];
        unsigned short h0 = f2bf(v0);
        Qh[m*136 + n0] = h0; Ql[m*136 + n0] = f2bf(v0 - bf2f(h0));
      }
    }
  }
  for (int e = tid; e < 16384; e += 512){
    int k = e >> 7, j = e & 127;
    float val = 0.f;
    if (j <= k) val = ldin(u_tril, (size_t)o*TRIL + (size_t)k*(k+1)/2 + j, isbf);
    unsigned short hi = f2bf(val);
    Sth[j*136 + k] = hi;
    Stl[j*136 + k] = f2bf(val - bf2f(hi));
  }
  __syncthreads();   // Qh/Ql + Sth/Stl visible
  // ---- phase P: P = Q*S via MFMA, 3 passes ----
  f32x4 acc3[8];
  #pragma unroll
  for (int mt=0; mt<8; ++mt) acc3[mt]=z4;
  #pragma unroll
  for (int kc2 = 0; kc2 < 4; ++kc2){
    const int ko = kc2*32 + q*8;
    short8 b0h = *(const short8*)(Sth + (wn + l15)*136 + ko);
    short8 b0l = *(const short8*)(Stl + (wn + l15)*136 + ko);
    #pragma unroll
    for (int mt=0; mt<8; ++mt){
      short8 ah = *(const short8*)(Qh + (mt*16 + l15)*136 + ko);
      short8 al = *(const short8*)(Ql + (mt*16 + l15)*136 + ko);
      acc3[mt] = __builtin_amdgcn_mfma_f32_16x16x32_bf16(ah, b0h, acc3[mt], 0,0,0);
      acc3[mt] = __builtin_amdgcn_mfma_f32_16x16x32_bf16(al, b0h, acc3[mt], 0,0,0);
      acc3[mt] = __builtin_amdgcn_mfma_f32_16x16x32_bf16(ah, b0l, acc3[mt], 0,0,0);
    }
  }
  __syncthreads();   // all Qh/Ql reads done before overwrite with Ph/Pl
  // ---- write P dense bf16 hi/lo over Qh/Ql ----
  {
    const int n0 = wn + l15;
    #pragma unroll
    for (int mt=0; mt<8; ++mt){
      #pragma unroll
      for (int r=0; r<4; ++r){
        int m = mt*16 + q*4 + r;
        float v0 = acc3[mt][r];
        unsigned short h0 = f2bf(v0);
        Qh[m*136 + n0] = h0; Ql[m*136 + n0] = f2bf(v0 - bf2f(h0));
      }
    }
  }
  __syncthreads();
  // ---- phase PP^T: self cross-product, hi/lo 3-pass MFMA ----
  f32x4 acc2[8];
  #pragma unroll
  for (int mt=0; mt<8; ++mt) acc2[mt]=z4;
  #pragma unroll
  for (int kc2 = 0; kc2 < 4; ++kc2){
    const int ko = kc2*32 + q*8;
    short8 b0h = *(const short8*)(Qh + (wn + l15)*136 + ko);
    short8 b0l = *(const short8*)(Ql + (wn + l15)*136 + ko);
    #pragma unroll
    for (int mt=0; mt<8; ++mt){
      short8 ah = *(const short8*)(Qh + (mt*16 + l15)*136 + ko);
      short8 al = *(const short8*)(Ql + (mt*16 + l15)*136 + ko);
      acc2[mt] = __builtin_amdgcn_mfma_f32_16x16x32_bf16(ah, b0h, acc2[mt], 0,0,0);
      acc2[mt] = __builtin_amdgcn_mfma_f32_16x16x32_bf16(ah, b0l, acc2[mt], 0,0,0);
      acc2[mt] = __builtin_amdgcn_mfma_f32_16x16x32_bf16(al, b0h, acc2[mt], 0,0,0);
    }
  }
  // ---- C epilogue: C = Q(regs) - PP^T -> bf16 hi/lo global ----
  {
    const size_t vbase = (size_t)ho * 16384;
    const int n = wn + l15;
    #pragma unroll
    for (int mt=0; mt<8; ++mt){
      #pragma unroll
      for (int r=0; r<4; ++r){
        int m = mt*16 + q*4 + r;
        float c = acc[mt][r] - acc2[mt][r];
        unsigned short hi = f2bf(c);
        unsigned short lo = f2bf(c - bf2f(hi));
        Chi[vbase + m*128 + n] = hi;
        Clo[vbase + m*128 + n] = lo;
      }
    }
  }
}

// ---------------- K9: fused main — kuf + mu + quadratic-form var -------------------
// BN=256: each block handles 256 x-cols (grid 16x64). B-operand in registers
// (double-buffered); only z staged via 3-buffer gl_lds + counted vmcnt.
__global__ __launch_bounds__(256, 2) void k_main(
    const unsigned short* __restrict__ zs, const unsigned short* __restrict__ xs,
    const float* __restrict__ zn2, const float* __restrict__ xn2,
    const float* __restrict__ wg, const unsigned short* __restrict__ Chi,
    const unsigned short* __restrict__ Clo, const float* __restrict__ sf2,
    const int* flagp, void* __restrict__ out){
  const int bblk = blockIdx.x, ho = blockIdx.y, h = ho >> 5;
  const int tid = threadIdx.x;
  const int lane = tid & 63, l15 = lane & 15, q = lane >> 4;
  const int wid = tid >> 6;
  const int wn = wid * 32;        // z-staging row split
  const int wn2 = wid * 64;       // output-column split (BN=256 / 4 waves)
  const int isbf = *flagp;
  extern __shared__ char smem[];
  unsigned short* zb0 = (unsigned short*)smem;          // [128][32] (8 KB each)
  unsigned short* zb1 = zb0 + 4096;
  unsigned short* zb2 = zb0 + 8192;
  unsigned short* kufT = (unsigned short*)smem;         // [256][136] (phase 2, aliases)
  float* zn2l = (float*)(smem + 69632);                 // [128]
  float* xn2l = zn2l + 128;                             // [256]
  float* wl   = xn2l + 256;                             // [128]

  if (tid < 128){
    zn2l[tid] = zn2[ho*128 + tid];
    wl[tid]   = wg[ho*128 + tid];
  }
  xn2l[tid] = xn2[(size_t)h*B_ + bblk*256 + tid];
  const size_t zbase = (size_t)ho * 32768;
  const size_t xbase = ((size_t)h*B_ + bblk*256) * 256;
  const int sw = ((q ^ ((l15 >> 1) & 3)) << 3);
  const int rA = wn + (lane >> 2);
  const int sg = ((lane & 3) ^ ((rA >> 1) & 3)) << 3;   // also valid for rA+16
  const f32x4 z4 = {0.f,0.f,0.f,0.f};
  f32x4 acc[8][4];
  #pragma unroll
  for (int mt=0; mt<8; ++mt){
    #pragma unroll
    for (int nt=0; nt<4; ++nt) acc[mt][nt]=z4;
  }
  unsigned short* zbp[3] = { zb0, zb1, zb2 };

  auto STAGEZ = [&](int c, unsigned short* zd){
    const int off = c*32;
    gl_lds16(zs + zbase + (size_t)rA*256      + off + sg, zd + wn*32);
    gl_lds16(zs + zbase + (size_t)(rA+16)*256 + off + sg, zd + (wn+16)*32);
  };
  auto LDB = [&](int c, short8* bd){
    #pragma unroll
    for (int nt=0; nt<4; ++nt)
      bd[nt] = *(const short8*)(xs + xbase + (size_t)(wn2 + nt*16 + l15)*256 + c*32 + q*8);
  };

  short8 bA[4], bB[4];
  STAGEZ(0, zb0);
  STAGEZ(1, zb1);
  LDB(0, bA);

  #pragma unroll
  for (int kc = 0; kc < 8; ++kc){
    unsigned short* zc = zbp[kc % 3];
    if (kc + 2 < 8) STAGEZ(kc + 2, zbp[(kc + 2) % 3]);
    if (kc + 1 < 8){ if (kc & 1) LDB(kc + 1, bA); else LDB(kc + 1, bB); }
    if (kc < 6)       asm volatile("s_waitcnt vmcnt(6)" ::: "memory");
    else if (kc == 6) asm volatile("s_waitcnt vmcnt(4)" ::: "memory");
    else              asm volatile("s_waitcnt vmcnt(0)" ::: "memory");
    __builtin_amdgcn_s_barrier();           // all waves' z chunk-kc landed
    __builtin_amdgcn_sched_barrier(0);
    const short8* bc = (kc & 1) ? bB : bA;
    #pragma unroll
    for (int mt=0; mt<8; ++mt){
      short8 a = *(const short8*)(zc + (mt*16 + l15)*32 + sw);
      #pragma unroll
      for (int nt=0; nt<4; ++nt)
        acc[mt][nt] = __builtin_amdgcn_mfma_f32_16x16x32_bf16(a, bc[nt], acc[mt][nt], 0,0,0);
    }
    asm volatile("s_waitcnt lgkmcnt(0)" ::: "memory");  // own ds_reads complete
    __builtin_amdgcn_sched_barrier(0);
    __builtin_amdgcn_s_barrier();           // all waves done reading buf[kc%3]
  }
  // phase 1 epilogue: kuf = sf2*exp(-0.5*d2); mu partial; store bf16 kufT
  const float s2 = sf2[h];
  float mu[4] = {0.f, 0.f, 0.f, 0.f};
  #pragma unroll
  for (int nt=0; nt<4; ++nt){
    const int bl = wn2 + nt*16 + l15;
    const float xn = xn2l[bl];
    #pragma unroll
    for (int mt=0; mt<8; ++mt){
      const int m0 = mt*16 + q*4;
      float kf[4];
      #pragma unroll
      for (int r=0; r<4; ++r){
        float d2 = fmaxf(zn2l[m0+r] + xn - 2.f*acc[mt][nt][r], 0.f);
        kf[r] = s2 * __expf(-0.5f*d2);
        mu[nt] += wl[m0+r] * kf[r];
      }
      uint2 pk;
      pk.x = (unsigned)f2bf(kf[0]) | ((unsigned)f2bf(kf[1]) << 16);
      pk.y = (unsigned)f2bf(kf[2]) | ((unsigned)f2bf(kf[3]) << 16);
      *(uint2*)(kufT + (size_t)bl*136 + m0) = pk;
    }
  }
  __syncthreads();
  // phase 2: T = (Chi + Clo) @ kuf   (K=128, 4 chunks of 32)
  f32x4 acc2[8][4];
  #pragma unroll
  for (int mt=0; mt<8; ++mt){
    #pragma unroll
    for (int nt=0; nt<4; ++nt) acc2[mt][nt]=z4;
  }
  const unsigned short* Ch = Chi + (size_t)ho*16384;
  const unsigned short* Cl = Clo + (size_t)ho*16384;
  #pragma unroll
  for (int kc2 = 0; kc2 < 4; ++kc2){
    short8 bk[4];
    #pragma unroll
    for (int nt=0; nt<4; ++nt)
      bk[nt] = *(const short8*)(kufT + (wn2 + nt*16 + l15)*136 + kc2*32 + q*8);
    #pragma unroll
    for (int mt=0; mt<8; ++mt){
      short8 ah = *(const short8*)(Ch + (mt*16 + l15)*128 + kc2*32 + q*8);
      short8 al = *(const short8*)(Cl + (mt*16 + l15)*128 + kc2*32 + q*8);
      #pragma unroll
      for (int nt=0; nt<4; ++nt){
        acc2[mt][nt] = __builtin_amdgcn_mfma_f32_16x16x32_bf16(ah, bk[nt], acc2[mt][nt], 0,0,0);
        acc2[mt][nt] = __builtin_amdgcn_mfma_f32_16x16x32_bf16(al, bk[nt], acc2[mt][nt], 0,0,0);
      }
    }
  }
  // phase 2 epilogue: s2p = sum_m kuf[m][b] * T[m][b]
  float s2p[4] = {0.f, 0.f, 0.f, 0.f};
  #pragma unroll
  for (int nt=0; nt<4; ++nt){
    const int bl = wn2 + nt*16 + l15;
    #pragma unroll
    for (int mt=0; mt<8; ++mt){
      const int m0 = mt*16 + q*4;
      uint2 pk = *(const uint2*)(kufT + (size_t)bl*136 + m0);
      f32x4 t = acc2[mt][nt];
      s2p[nt] += bf2f((unsigned short)(pk.x & 0xffff)) * t[0]
               + bf2f((unsigned short)(pk.x >> 16))    * t[1]
               + bf2f((unsigned short)(pk.y & 0xffff)) * t[2]
               + bf2f((unsigned short)(pk.y >> 16))    * t[3];
    }
  }
  #pragma unroll
  for (int nt=0; nt<4; ++nt){
    mu[nt]  += __shfl_xor(mu[nt], 16);  mu[nt]  += __shfl_xor(mu[nt], 32);
    s2p[nt] += __shfl_xor(s2p[nt], 16); s2p[nt] += __shfl_xor(s2p[nt], 32);
  }
  if (lane < 16){
    #pragma unroll
    for (int nt=0; nt<4; ++nt){
      size_t col = (size_t)ho*B_ + bblk*256 + wn2 + nt*16 + lane;
      stout(out, col,                  mu[nt],        isbf);
      stout(out, (size_t)HO*B_ + col,  s2 - s2p[nt],  isbf);
    }
  }
}

// ---------------- launch ----------------
extern "C" void kernel_launch(void* const* d_in, const int* in_sizes, int n_in,
                              void* d_out, int out_size, void* d_ws, size_t ws_size,
                              hipStream_t stream) {
  const void* x      = d_in[0];
  const void* z      = d_in[1];
  const void* u_mean = d_in[2];
  const void* u_tril = d_in[3];
  const void* theta  = d_in[4];
  char* ws = (char*)d_ws;

  int*   flag   = (int*)(ws + OFF_FLAG);
  float* inv_ls = (float*)(ws + OFF_INVLS);
  float* sf2    = (float*)(ws + OFF_SF2);
  float* zn2    = (float*)(ws + OFF_ZN2);
  float* xn2    = (float*)(ws + OFF_XN2);
  float* wv     = (float*)(ws + OFF_W);
  unsigned short* zsw = (unsigned short*)(ws + OFF_ZS);
  unsigned short* xsw = (unsigned short*)(ws + OFF_XS);
  unsigned short* Chi = (unsigned short*)(ws + OFF_CHI);
  unsigned short* Clo = (unsigned short*)(ws + OFF_CLO);

  k_hypers<<<1, 256, 0, stream>>>(theta, x, flag, inv_ls, sf2);
  k_scale<<<dim3(2048), 256, 0, stream>>>(x, z, flag, inv_ls, xsw, zsw, xn2, zn2);
  k_fact<<<64, 512, 156672, stream>>>(zsw, zn2, sf2, u_mean, u_tril, flag, wv, Chi, Clo);
  k_main<<<dim3(16, 64), 256, 69632 + 2048, stream>>>(zsw, xsw, zn2, xn2, wv, Chi, Clo, sf2, flag, (void*)d_out);
}

// Round 8
// 229.763 us; speedup vs baseline: 1.0563x; 1.0563x over previous
//
#include <hip/hip_runtime.h>
#include <cstdint>
#include <cstddef>

// ---------------- constants ----------------
constexpr int B_   = 4096;
constexpr int DIN  = 256;
constexpr int OUT_ = 32;
constexpr int MM   = 128;
constexpr int NH_  = 2;
constexpr int HO   = 64;          // NH*OUT
constexpr int TRIL = 8256;        // 128*129/2
constexpr float JIT = 1e-4f;

// ---------------- workspace layout ----------------
constexpr size_t al4k(size_t x){ return (x + 4095) & ~size_t(4095); }
constexpr size_t OFF_FLAG  = 0;                               // int
constexpr size_t OFF_INVLS = 4096;                            // f32 [2][256]
constexpr size_t OFF_SF2   = al4k(OFF_INVLS + 2*256*4);       // f32 [2]
constexpr size_t OFF_ZN2   = al4k(OFF_SF2 + 64);              // f32 [2][4096]
constexpr size_t OFF_XN2   = al4k(OFF_ZN2 + 8192*4);          // f32 [2][4096]
constexpr size_t OFF_W     = al4k(OFF_XN2 + 8192*4);          // f32 [64][128]
constexpr size_t OFF_ZS    = al4k(OFF_W + 8192*4);            // bf16 [2][4096][256]
constexpr size_t OFF_XS    = al4k(OFF_ZS + (size_t)2097152*2);
constexpr size_t OFF_VTH   = al4k(OFF_XS + (size_t)2097152*2); // (unused after merge)
constexpr size_t OFF_VTL   = al4k(OFF_VTH + (size_t)1048576*2);
constexpr size_t OFF_CHI   = al4k(OFF_VTL + (size_t)1048576*2);// bf16 [64][128][128]
constexpr size_t OFF_CLO   = al4k(OFF_CHI + (size_t)1048576*2);

typedef float f32x4 __attribute__((ext_vector_type(4)));
typedef short short8 __attribute__((ext_vector_type(8)));

__device__ __forceinline__ float bf2f(unsigned short u){
  union{unsigned int i; float f;} v; v.i = ((unsigned)u) << 16; return v.f;
}
__device__ __forceinline__ unsigned short f2bf(float f){
  union{float f; unsigned int i;} v; v.f = f;
  unsigned int r = v.i + 0x7fffu + ((v.i >> 16) & 1u);
  return (unsigned short)(r >> 16);
}
__device__ __forceinline__ float ldin(const void* p, size_t i, int isbf){
  if (isbf) return bf2f(((const unsigned short*)p)[i]);
  return ((const float*)p)[i];
}
__device__ __forceinline__ void stout(void* p, size_t i, float v, int isbf){
  if (isbf) ((unsigned short*)p)[i] = f2bf(v);
  else ((float*)p)[i] = v;
}
// async global->LDS, 16B per lane; LDS dest = wave-uniform base + lane*16
__device__ __forceinline__ void gl_lds16(const unsigned short* g, unsigned short* l){
  __builtin_amdgcn_global_load_lds(
      (const __attribute__((address_space(1))) unsigned int*)g,
      (__attribute__((address_space(3))) unsigned int*)l, 16, 0, 0);
}

// ---------------- K1: detect dtype + hypers (merged) ----------------
__global__ void k_hypers(const void* __restrict__ theta, const void* __restrict__ x,
                         int* __restrict__ flagp,
                         float* __restrict__ inv_ls, float* __restrict__ sf2){
  __shared__ int sflag;
  int t = threadIdx.x;
  if (t < 64){
    unsigned int w0 = ((const unsigned int*)theta)[t];
    unsigned int w1 = ((const unsigned int*)x)[t];
    float a0 = fabsf(bf2f((unsigned short)(w0 & 0xffffu)));
    float a1 = fabsf(bf2f((unsigned short)(w1 & 0xffffu)));
    int c = ((a0 > 9.3e-10f && a0 < 64.f) ? 1 : 0) + ((a1 > 9.3e-10f && a1 < 64.f) ? 1 : 0);
    c += __shfl_down(c, 32); c += __shfl_down(c, 16); c += __shfl_down(c, 8);
    c += __shfl_down(c, 4);  c += __shfl_down(c, 2);  c += __shfl_down(c, 1);
    if (t == 0){ sflag = (c >= 64) ? 1 : 0; *flagp = sflag; }
  }
  __syncthreads();
  const int isbf = sflag;
  for (int i = t; i < NH_*257; i += blockDim.x){
    int h = i / 257, j = i - h*257;
    float v = ldin(theta, i, isbf);
    if (j == 0) sf2[h] = __expf(v);
    else inv_ls[h*DIN + j - 1] = __expf(-v);
  }
}

// ---------------- K2: scale x and z by 1/ls -> bf16 + squared norms --------
__global__ void k_scale(const void* __restrict__ xsrc, const void* __restrict__ zsrc,
                        const int* flagp, const float* __restrict__ inv_ls,
                        unsigned short* __restrict__ xdst, unsigned short* __restrict__ zdst,
                        float* __restrict__ xn2, float* __restrict__ zn2){
  const int isbf = *flagp;
  const int wave = threadIdx.x >> 6, lane = threadIdx.x & 63;
  int bx = blockIdx.x;
  const void* src; unsigned short* dst; float* n2; int r;
  if (bx < 1024){ src = xsrc; dst = xdst; n2 = xn2; r = bx*4 + wave; }
  else          { src = zsrc; dst = zdst; n2 = zn2; r = (bx-1024)*4 + wave; }
  const int d0 = lane*4;
  float v[4];
  if (isbf){
    uint2 uu = *(const uint2*)((const unsigned short*)src + (size_t)r*DIN + d0);
    v[0]=bf2f((unsigned short)(uu.x & 0xffffu)); v[1]=bf2f((unsigned short)(uu.x >> 16));
    v[2]=bf2f((unsigned short)(uu.y & 0xffffu)); v[3]=bf2f((unsigned short)(uu.y >> 16));
  } else {
    f32x4 f = *(const f32x4*)((const float*)src + (size_t)r*DIN + d0);
    v[0]=f[0]; v[1]=f[1]; v[2]=f[2]; v[3]=f[3];
  }
  #pragma unroll
  for (int h = 0; h < 2; ++h){
    f32x4 il = *(const f32x4*)(inv_ls + h*DIN + d0);
    unsigned short rb[4];
    float p = 0.f;
    #pragma unroll
    for (int k = 0; k < 4; ++k){
      float s = v[k] * il[k];
      rb[k] = f2bf(s);
      float qv = bf2f(rb[k]);
      p += qv*qv;
    }
    uint2 pk;
    pk.x = (unsigned)rb[0] | ((unsigned)rb[1] << 16);
    pk.y = (unsigned)rb[2] | ((unsigned)rb[3] << 16);
    *(uint2*)(dst + ((size_t)h*4096 + r)*DIN + d0) = pk;
    p += __shfl_xor(p, 32); p += __shfl_xor(p, 16); p += __shfl_xor(p, 8);
    p += __shfl_xor(p, 4);  p += __shfl_xor(p, 2);  p += __shfl_xor(p, 1);
    if (lane == 0) n2[(size_t)h*4096 + r] = p;
  }
}

// ---------------- K3: FUSED kuu + Cholesky + trtri + Q/w/P/C (one kernel) ----------
// 512 threads / 8 waves. LDS regions (153 KB total):
//   A [0..82432):      float T tiles (80.5KB) + zn2l; later aliased by Sth/Stl
//   B [82432..152064): kuu z-staging bufs (3x8KB), then VT hi/lo, then Qh/Ql, Ph/Pl
//   floats [152064..): ul[128], wpart[8][128]
// Cholesky is the SEQUENTIAL round-5 schedule (lookahead variant regressed 45%,
// r6/r7: VGPR 92->124 and uniform slowdown; reverted). kuu staging keeps the
// 3-buffer counted-vmcnt pipeline (A/B attribution vs round 5's sync-sync).
constexpr int TLD = 20;          // tile leading dim (floats)
constexpr int TSZ = 16*TLD;      // 320 floats per tile
__device__ __forceinline__ int tb(int bi, int bj){ return (bi*(bi+1)/2 + bj)*TSZ; }
__device__ __forceinline__ int vb(int bi, int bj){ return (36 + bi*(bi-1)/2 + bj)*TSZ; }
__device__ __forceinline__ int tri_bi(int t){
  int bi = (int)((sqrtf(8.f*t + 1.f) - 1.f) * 0.5f);
  while ((bi+1)*(bi+2)/2 <= t) ++bi;
  while (bi*(bi+1)/2 > t) --bi;
  return bi;
}

__global__ __launch_bounds__(512) void k_fact(
    const unsigned short* __restrict__ zs, const float* __restrict__ zn2,
    const float* __restrict__ sf2,
    const void* __restrict__ u_mean, const void* __restrict__ u_tril,
    const int* flagp, float* __restrict__ wg,
    unsigned short* __restrict__ Chi, unsigned short* __restrict__ Clo){
  const int ho = blockIdx.x, h = ho >> 5, o = ho & 31;
  const int tid = threadIdx.x;
  const int lane = tid & 63, wid = tid >> 6;      // 8 waves
  const int l15 = lane & 15, q = lane >> 4;
  const int wn = wid * 16;                        // 16 output-cols per wave
  const int isbf = *flagp;
  extern __shared__ char smem[];
  float* T = (float*)smem;                            // 64 tiles
  float* zn2l = T + 64*TSZ;                           // [128] @81920
  unsigned short* VTh = (unsigned short*)(smem + 82432);   // [128][136]
  unsigned short* VTl = (unsigned short*)(smem + 117248);  // [128][136]
  unsigned short* Sth = (unsigned short*)smem;             // alias A (post-trtri)
  unsigned short* Stl = (unsigned short*)(smem + 34816);
  unsigned short* Qh = VTh;                                // alias B (post-Q-phase)
  unsigned short* Ql = VTl;
  float* ul    = (float*)(smem + 152064);             // [128]
  float* wpart = (float*)(smem + 152576);             // [8][128]
  // kuu z-staging triple buffer, aliases region B (dead until VT conversion)
  unsigned short* zbB0 = (unsigned short*)(smem + 82432);
  unsigned short* zbB1 = (unsigned short*)(smem + 90624);
  unsigned short* zbB2 = (unsigned short*)(smem + 98816);
  unsigned short* zbB[3] = { zbB0, zbB1, zbB2 };

  if (tid < 128){
    zn2l[tid] = zn2[ho*128 + tid];
    ul[tid]   = ldin(u_mean, (size_t)o*128 + tid, isbf);
  }
  const size_t zbase = (size_t)ho * 32768;
  const int sw = ((q ^ ((l15 >> 1) & 3)) << 3);
  const int rA = wn + (lane >> 2);
  const int sg = ((lane & 3) ^ ((rA >> 1) & 3)) << 3;
  const f32x4 z4 = {0.f,0.f,0.f,0.f};

  auto STAGEZ = [&](int c, unsigned short* zd){
    gl_lds16(zs + zbase + (size_t)rA*256 + c*32 + sg, zd + wn*32);
  };

  // ---- phase kuu: zs zs^T via MFMA, 3-buffer counted-vmcnt pipeline ----
  f32x4 acck[8];
  #pragma unroll
  for (int mt=0; mt<8; ++mt) acck[mt]=z4;
  STAGEZ(0, zbB0);
  STAGEZ(1, zbB1);
  __syncthreads();   // full drain: zn2l/ul + stages 0,1 landed; LDS visible
  #pragma unroll
  for (int kc = 0; kc < 8; ++kc){
    unsigned short* zc = zbB[kc % 3];
    if (kc + 2 < 8) STAGEZ(kc + 2, zbB[(kc + 2) % 3]);
    // per-wave loads: 1 per STAGEZ; in flight <= chunks kc+1, kc+2
    if (kc < 6)       asm volatile("s_waitcnt vmcnt(2)" ::: "memory");
    else if (kc == 6) asm volatile("s_waitcnt vmcnt(1)" ::: "memory");
    else              asm volatile("s_waitcnt vmcnt(0)" ::: "memory");
    __builtin_amdgcn_s_barrier();           // all waves' chunk-kc landed
    __builtin_amdgcn_sched_barrier(0);
    short8 b0 = *(const short8*)(zc + (wn + l15)*32 + sw);
    #pragma unroll
    for (int mt=0; mt<8; ++mt){
      short8 a = *(const short8*)(zc + (mt*16 + l15)*32 + sw);
      acck[mt] = __builtin_amdgcn_mfma_f32_16x16x32_bf16(a, b0, acck[mt], 0,0,0);
    }
    asm volatile("s_waitcnt lgkmcnt(0)" ::: "memory");
    __builtin_amdgcn_sched_barrier(0);
    __builtin_amdgcn_s_barrier();           // reads done before buf reuse
  }
  // ---- epilogue: kuu -> T tiles (lower + full diag), + jitter ----
  const float s2v = sf2[h];
  {
    const int n = wn + l15;
    const float nn = zn2l[n];
    const int bn = wid;
    #pragma unroll
    for (int mt=0; mt<8; ++mt){
      #pragma unroll
      for (int r=0; r<4; ++r){
        int m = mt*16 + q*4 + r;
        float d2 = fmaxf(zn2l[m] + nn - 2.f*acck[mt][r], 0.f);
        float a = s2v * __expf(-0.5f*d2);
        if (m == n) a += JIT;
        int bm = m >> 4;
        if (bn <= bm) T[tb(bm, bn) + (m & 15)*TLD + (n & 15)] = a;
      }
    }
  }
  __syncthreads();
  // ---- blocked Cholesky, panel width 16 (sequential round-5 schedule) ----
  for (int kb = 0; kb < 8; ++kb){
    if (wid == 0){
      float* D = T + tb(kb, kb);
      const int r = lane & 15;
      const bool act = (lane < 16);
      float a[16];
      #pragma unroll
      for (int k = 0; k < 16; ++k) a[k] = 0.f;
      if (act){
        #pragma unroll
        for (int k2 = 0; k2 < 4; ++k2)
          *(f32x4*)(a + 4*k2) = *(const f32x4*)(D + r*TLD + 4*k2);
      }
      #pragma unroll
      for (int c = 0; c < 16; ++c){
        float pr[16];
        #pragma unroll
        for (int k = 0; k < 16; ++k) pr[k] = __shfl(a[k], c);
        float rsq = rsqrtf(pr[c]);
        if (act && r >= c) a[c] *= rsq;
        float lrc = a[c];
        #pragma unroll
        for (int k = 0; k < 16; ++k)
          if (k > c && act && r > c) a[k] -= lrc * (pr[k] * rsq);
      }
      float v[16];
      #pragma unroll
      for (int k = 0; k < 16; ++k) v[k] = 0.f;
      const int c = lane & 15;
      #pragma unroll
      for (int i = 0; i < 16; ++i){
        float lrow[16];
        #pragma unroll
        for (int k = 0; k < 16; ++k) lrow[k] = __shfl(a[k], i);
        float rli = 1.f / lrow[i];
        float s = 0.f;
        #pragma unroll
        for (int k = 0; k < 16; ++k)
          if (k < i) s += ((k >= c) ? lrow[k]*v[k] : 0.f);
        v[i] = (c == i) ? rli : ((c < i) ? -s*rli : 0.f);
      }
      if (act){
        #pragma unroll
        for (int i = 0; i < 16; ++i) D[i*TLD + c] = v[i];
      }
    }
    __syncthreads();
    {
      const int gi = kb*16 + 16 + tid;
      if (gi < 128){
        float* Bp = T + tb(gi >> 4, kb) + (gi & 15)*TLD;
        const float* Vd = T + tb(kb, kb);
        float b[16], nb[16];
        #pragma unroll
        for (int k2 = 0; k2 < 4; ++k2) *(f32x4*)(b + 4*k2) = *(const f32x4*)(Bp + 4*k2);
        #pragma unroll
        for (int j = 0; j < 16; ++j){
          float s = 0.f;
          #pragma unroll
          for (int k = 0; k < 16; ++k)
            if (k <= j) s += b[k] * Vd[j*TLD + k];
          nb[j] = s;
        }
        #pragma unroll
        for (int k2 = 0; k2 < 4; ++k2) *(f32x4*)(Bp + 4*k2) = *(const f32x4*)(nb + 4*k2);
      }
    }
    __syncthreads();
    {
      const int D8 = 7 - kb;
      const int Tn = D8*(D8+1)/2;
      const int r15 = lane & 15, c0 = (lane >> 4)*4;
      for (int tt = wid; tt < Tn; tt += 8){
        int bi1 = tri_bi(tt);
        int bj1 = tt - bi1*(bi1+1)/2;
        int bi = kb + 1 + bi1, bj = kb + 1 + bj1;
        const float* Lr = T + tb(bi, kb) + r15*TLD;
        const float* Lc = T + tb(bj, kb) + c0*TLD;
        float* Cp = T + tb(bi, bj) + r15*TLD + c0;
        float lr[16];
        #pragma unroll
        for (int k2 = 0; k2 < 4; ++k2) *(f32x4*)(lr + 4*k2) = *(const f32x4*)(Lr + 4*k2);
        f32x4 accv = *(const f32x4*)Cp;
        #pragma unroll
        for (int cc = 0; cc < 4; ++cc){
          float lc[16];
          #pragma unroll
          for (int k2 = 0; k2 < 4; ++k2) *(f32x4*)(lc + 4*k2) = *(const f32x4*)(Lc + cc*TLD + 4*k2);
          float s = 0.f;
          #pragma unroll
          for (int k = 0; k < 16; ++k) s += lr[k]*lc[k];
          accv[cc] -= s;
        }
        *(f32x4*)Cp = accv;
      }
    }
    __syncthreads();
  }
  // ---- trtri by anti-diagonal wavefronts ----
  {
    const int r15 = lane & 15, c0 = (lane >> 4)*4;
    for (int d = 1; d < 8; ++d){
      for (int tt = wid; tt < 8 - d; tt += 8){
        const int bi = d + tt, jb = bi - d;
        float W0=0.f, W1=0.f, W2=0.f, W3=0.f;
        for (int k = jb; k < bi; ++k){
          const float* Lt = T + tb(bi, k) + r15*TLD;
          const float* Vt = (k == jb) ? (T + tb(jb, jb)) : (T + vb(k, jb));
          float lr[16];
          #pragma unroll
          for (int k2 = 0; k2 < 4; ++k2) *(f32x4*)(lr + 4*k2) = *(const f32x4*)(Lt + 4*k2);
          #pragma unroll
          for (int kk = 0; kk < 16; ++kk){
            f32x4 vv = *(const f32x4*)(Vt + kk*TLD + c0);
            W0 += lr[kk]*vv[0]; W1 += lr[kk]*vv[1];
            W2 += lr[kk]*vv[2]; W3 += lr[kk]*vv[3];
          }
        }
        const float* Vd = T + tb(bi, bi) + r15*TLD;
        const int cgl = (lane >> 4);
        f32x4 Rr = {0.f,0.f,0.f,0.f};
        #pragma unroll
        for (int k = 0; k < 16; ++k){
          float vd = Vd[k];
          float w0 = __shfl(W0, (cgl<<4)|k);
          float w1 = __shfl(W1, (cgl<<4)|k);
          float w2 = __shfl(W2, (cgl<<4)|k);
          float w3 = __shfl(W3, (cgl<<4)|k);
          Rr[0] -= vd*w0; Rr[1] -= vd*w1; Rr[2] -= vd*w2; Rr[3] -= vd*w3;
        }
        *(f32x4*)(T + vb(bi, jb) + r15*TLD + c0) = Rr;
      }
      __syncthreads();
    }
  }
  // ---- convert V (T tiles) -> VT bf16 hi/lo in LDS region B: VT[c][r]=V[r][c] ----
  for (int e = tid; e < 16384; e += 512){
    int c = e >> 7, rr = e & 127;
    int bc = c >> 4, br = rr >> 4;
    float v = 0.f;
    if (br == bc)      v = T[tb(br, bc) + (rr & 15)*TLD + (c & 15)];
    else if (br > bc)  v = T[vb(br, bc) + (rr & 15)*TLD + (c & 15)];
    unsigned short hi = f2bf(v);
    VTh[c*136 + rr] = hi;
    VTl[c*136 + rr] = f2bf(v - bf2f(hi));
  }
  __syncthreads();   // VT complete (and all T reads done -> A free after this phase)
  // ---- phase Q: Q = VT * VT^T via hi/lo 3-pass MFMA, pure LDS reads ----
  f32x4 acc[8];
  #pragma unroll
  for (int mt=0; mt<8; ++mt) acc[mt]=z4;
  #pragma unroll
  for (int kc2 = 0; kc2 < 4; ++kc2){
    const int ko = kc2*32 + q*8;
    short8 b0h = *(const short8*)(VTh + (wn + l15)*136 + ko);
    short8 b0l = *(const short8*)(VTl + (wn + l15)*136 + ko);
    #pragma unroll
    for (int mt=0; mt<8; ++mt){
      short8 ah = *(const short8*)(VTh + (mt*16 + l15)*136 + ko);
      short8 al = *(const short8*)(VTl + (mt*16 + l15)*136 + ko);
      acc[mt] = __builtin_amdgcn_mfma_f32_16x16x32_bf16(ah, b0h, acc[mt], 0,0,0);
      acc[mt] = __builtin_amdgcn_mfma_f32_16x16x32_bf16(ah, b0l, acc[mt], 0,0,0);
      acc[mt] = __builtin_amdgcn_mfma_f32_16x16x32_bf16(al, b0h, acc[mt], 0,0,0);
    }
  }
  // ---- w = Q u (shuffle reduce over the wave's 16 cols) ----
  {
    float u0 = ul[wn + l15];
    float wpm[32];
    #pragma unroll
    for (int mt=0; mt<8; ++mt){
      #pragma unroll
      for (int r=0; r<4; ++r)
        wpm[mt*4+r] = acc[mt][r]*u0;
    }
    #pragma unroll
    for (int i = 0; i < 32; ++i){
      wpm[i] += __shfl_xor(wpm[i], 1);
      wpm[i] += __shfl_xor(wpm[i], 2);
      wpm[i] += __shfl_xor(wpm[i], 4);
      wpm[i] += __shfl_xor(wpm[i], 8);
    }
    if (l15 == 0){
      #pragma unroll
      for (int i = 0; i < 32; ++i){
        int m = (i>>2)*16 + q*4 + (i&3);
        wpart[wid*128 + m] = wpm[i];
      }
    }
  }
  __syncthreads();   // all Q-phase VT reads done (B free to overwrite) + wpart visible
  if (tid < 128){
    float s = 0.f;
    #pragma unroll
    for (int wv = 0; wv < 8; ++wv) s += wpart[wv*128 + tid];
    wg[ho*128 + tid] = s;
  }
  // ---- write Q dense bf16 hi/lo over VT (B); fill St = S^T over T (A) ----
  {
    const int n0 = wn + l15;
    #pragma unroll
    for (int mt=0; mt<8; ++mt){
      #pragma unroll
      for (int r=0; r<4; ++r){
        int m = mt*16 + q*4 + r;
        float v0 = acc[mt][r];
        unsigned short h0 = f2bf(v0);
        Qh[m*136 + n0] = h0; Ql[m*136 + n0] = f2bf(v0 - bf2f(h0));
      }
    }
  }
  for (int e = tid; e < 16384; e += 512){
    int k = e >> 7, j = e & 127;
    float val = 0.f;
    if (j <= k) val = ldin(u_tril, (size_t)o*TRIL + (size_t)k*(k+1)/2 + j, isbf);
    unsigned short hi = f2bf(val);
    Sth[j*136 + k] = hi;
    Stl[j*136 + k] = f2bf(val - bf2f(hi));
  }
  __syncthreads();   // Qh/Ql + Sth/Stl visible
  // ---- phase P: P = Q*S via MFMA, 3 passes ----
  f32x4 acc3[8];
  #pragma unroll
  for (int mt=0; mt<8; ++mt) acc3[mt]=z4;
  #pragma unroll
  for (int kc2 = 0; kc2 < 4; ++kc2){
    const int ko = kc2*32 + q*8;
    short8 b0h = *(const short8*)(Sth + (wn + l15)*136 + ko);
    short8 b0l = *(const short8*)(Stl + (wn + l15)*136 + ko);
    #pragma unroll
    for (int mt=0; mt<8; ++mt){
      short8 ah = *(const short8*)(Qh + (mt*16 + l15)*136 + ko);
      short8 al = *(const short8*)(Ql + (mt*16 + l15)*136 + ko);
      acc3[mt] = __builtin_amdgcn_mfma_f32_16x16x32_bf16(ah, b0h, acc3[mt], 0,0,0);
      acc3[mt] = __builtin_amdgcn_mfma_f32_16x16x32_bf16(al, b0h, acc3[mt], 0,0,0);
      acc3[mt] = __builtin_amdgcn_mfma_f32_16x16x32_bf16(ah, b0l, acc3[mt], 0,0,0);
    }
  }
  __syncthreads();   // all Qh/Ql reads done before overwrite with Ph/Pl
  // ---- write P dense bf16 hi/lo over Qh/Ql ----
  {
    const int n0 = wn + l15;
    #pragma unroll
    for (int mt=0; mt<8; ++mt){
      #pragma unroll
      for (int r=0; r<4; ++r){
        int m = mt*16 + q*4 + r;
        float v0 = acc3[mt][r];
        unsigned short h0 = f2bf(v0);
        Qh[m*136 + n0] = h0; Ql[m*136 + n0] = f2bf(v0 - bf2f(h0));
      }
    }
  }
  __syncthreads();
  // ---- phase PP^T: self cross-product, hi/lo 3-pass MFMA ----
  f32x4 acc2[8];
  #pragma unroll
  for (int mt=0; mt<8; ++mt) acc2[mt]=z4;
  #pragma unroll
  for (int kc2 = 0; kc2 < 4; ++kc2){
    const int ko = kc2*32 + q*8;
    short8 b0h = *(const short8*)(Qh + (wn + l15)*136 + ko);
    short8 b0l = *(const short8*)(Ql + (wn + l15)*136 + ko);
    #pragma unroll
    for (int mt=0; mt<8; ++mt){
      short8 ah = *(const short8*)(Qh + (mt*16 + l15)*136 + ko);
      short8 al = *(const short8*)(Ql + (mt*16 + l15)*136 + ko);
      acc2[mt] = __builtin_amdgcn_mfma_f32_16x16x32_bf16(ah, b0h, acc2[mt], 0,0,0);
      acc2[mt] = __builtin_amdgcn_mfma_f32_16x16x32_bf16(ah, b0l, acc2[mt], 0,0,0);
      acc2[mt] = __builtin_amdgcn_mfma_f32_16x16x32_bf16(al, b0h, acc2[mt], 0,0,0);
    }
  }
  // ---- C epilogue: C = Q(regs) - PP^T -> bf16 hi/lo global ----
  {
    const size_t vbase = (size_t)ho * 16384;
    const int n = wn + l15;
    #pragma unroll
    for (int mt=0; mt<8; ++mt){
      #pragma unroll
      for (int r=0; r<4; ++r){
        int m = mt*16 + q*4 + r;
        float c = acc[mt][r] - acc2[mt][r];
        unsigned short hi = f2bf(c);
        unsigned short lo = f2bf(c - bf2f(hi));
        Chi[vbase + m*128 + n] = hi;
        Clo[vbase + m*128 + n] = lo;
      }
    }
  }
}

// ---------------- K9: fused main — kuf + mu + quadratic-form var -------------------
// BN=256: each block handles 256 x-cols (grid 16x64). B-operand in registers
// (double-buffered); only z staged via 3-buffer gl_lds + counted vmcnt.
__global__ __launch_bounds__(256, 2) void k_main(
    const unsigned short* __restrict__ zs, const unsigned short* __restrict__ xs,
    const float* __restrict__ zn2, const float* __restrict__ xn2,
    const float* __restrict__ wg, const unsigned short* __restrict__ Chi,
    const unsigned short* __restrict__ Clo, const float* __restrict__ sf2,
    const int* flagp, void* __restrict__ out){
  const int bblk = blockIdx.x, ho = blockIdx.y, h = ho >> 5;
  const int tid = threadIdx.x;
  const int lane = tid & 63, l15 = lane & 15, q = lane >> 4;
  const int wid = tid >> 6;
  const int wn = wid * 32;        // z-staging row split
  const int wn2 = wid * 64;       // output-column split (BN=256 / 4 waves)
  const int isbf = *flagp;
  extern __shared__ char smem[];
  unsigned short* zb0 = (unsigned short*)smem;          // [128][32] (8 KB each)
  unsigned short* zb1 = zb0 + 4096;
  unsigned short* zb2 = zb0 + 8192;
  unsigned short* kufT = (unsigned short*)smem;         // [256][136] (phase 2, aliases)
  float* zn2l = (float*)(smem + 69632);                 // [128]
  float* xn2l = zn2l + 128;                             // [256]
  float* wl   = xn2l + 256;                             // [128]

  if (tid < 128){
    zn2l[tid] = zn2[ho*128 + tid];
    wl[tid]   = wg[ho*128 + tid];
  }
  xn2l[tid] = xn2[(size_t)h*B_ + bblk*256 + tid];
  const size_t zbase = (size_t)ho * 32768;
  const size_t xbase = ((size_t)h*B_ + bblk*256) * 256;
  const int sw = ((q ^ ((l15 >> 1) & 3)) << 3);
  const int rA = wn + (lane >> 2);
  const int sg = ((lane & 3) ^ ((rA >> 1) & 3)) << 3;   // also valid for rA+16
  const f32x4 z4 = {0.f,0.f,0.f,0.f};
  f32x4 acc[8][4];
  #pragma unroll
  for (int mt=0; mt<8; ++mt){
    #pragma unroll
    for (int nt=0; nt<4; ++nt) acc[mt][nt]=z4;
  }
  unsigned short* zbp[3] = { zb0, zb1, zb2 };

  auto STAGEZ = [&](int c, unsigned short* zd){
    const int off = c*32;
    gl_lds16(zs + zbase + (size_t)rA*256      + off + sg, zd + wn*32);
    gl_lds16(zs + zbase + (size_t)(rA+16)*256 + off + sg, zd + (wn+16)*32);
  };
  auto LDB = [&](int c, short8* bd){
    #pragma unroll
    for (int nt=0; nt<4; ++nt)
      bd[nt] = *(const short8*)(xs + xbase + (size_t)(wn2 + nt*16 + l15)*256 + c*32 + q*8);
  };

  short8 bA[4], bB[4];
  STAGEZ(0, zb0);
  STAGEZ(1, zb1);
  LDB(0, bA);

  #pragma unroll
  for (int kc = 0; kc < 8; ++kc){
    unsigned short* zc = zbp[kc % 3];
    if (kc + 2 < 8) STAGEZ(kc + 2, zbp[(kc + 2) % 3]);
    if (kc + 1 < 8){ if (kc & 1) LDB(kc + 1, bA); else LDB(kc + 1, bB); }
    if (kc < 6)       asm volatile("s_waitcnt vmcnt(6)" ::: "memory");
    else if (kc == 6) asm volatile("s_waitcnt vmcnt(4)" ::: "memory");
    else              asm volatile("s_waitcnt vmcnt(0)" ::: "memory");
    __builtin_amdgcn_s_barrier();           // all waves' z chunk-kc landed
    __builtin_amdgcn_sched_barrier(0);
    const short8* bc = (kc & 1) ? bB : bA;
    #pragma unroll
    for (int mt=0; mt<8; ++mt){
      short8 a = *(const short8*)(zc + (mt*16 + l15)*32 + sw);
      #pragma unroll
      for (int nt=0; nt<4; ++nt)
        acc[mt][nt] = __builtin_amdgcn_mfma_f32_16x16x32_bf16(a, bc[nt], acc[mt][nt], 0,0,0);
    }
    asm volatile("s_waitcnt lgkmcnt(0)" ::: "memory");  // own ds_reads complete
    __builtin_amdgcn_sched_barrier(0);
    __builtin_amdgcn_s_barrier();           // all waves done reading buf[kc%3]
  }
  // phase 1 epilogue: kuf = sf2*exp(-0.5*d2); mu partial; store bf16 kufT
  const float s2 = sf2[h];
  float mu[4] = {0.f, 0.f, 0.f, 0.f};
  #pragma unroll
  for (int nt=0; nt<4; ++nt){
    const int bl = wn2 + nt*16 + l15;
    const float xn = xn2l[bl];
    #pragma unroll
    for (int mt=0; mt<8; ++mt){
      const int m0 = mt*16 + q*4;
      float kf[4];
      #pragma unroll
      for (int r=0; r<4; ++r){
        float d2 = fmaxf(zn2l[m0+r] + xn - 2.f*acc[mt][nt][r], 0.f);
        kf[r] = s2 * __expf(-0.5f*d2);
        mu[nt] += wl[m0+r] * kf[r];
      }
      uint2 pk;
      pk.x = (unsigned)f2bf(kf[0]) | ((unsigned)f2bf(kf[1]) << 16);
      pk.y = (unsigned)f2bf(kf[2]) | ((unsigned)f2bf(kf[3]) << 16);
      *(uint2*)(kufT + (size_t)bl*136 + m0) = pk;
    }
  }
  __syncthreads();
  // phase 2: T = (Chi + Clo) @ kuf   (K=128, 4 chunks of 32)
  f32x4 acc2[8][4];
  #pragma unroll
  for (int mt=0; mt<8; ++mt){
    #pragma unroll
    for (int nt=0; nt<4; ++nt) acc2[mt][nt]=z4;
  }
  const unsigned short* Ch = Chi + (size_t)ho*16384;
  const unsigned short* Cl = Clo + (size_t)ho*16384;
  #pragma unroll
  for (int kc2 = 0; kc2 < 4; ++kc2){
    short8 bk[4];
    #pragma unroll
    for (int nt=0; nt<4; ++nt)
      bk[nt] = *(const short8*)(kufT + (wn2 + nt*16 + l15)*136 + kc2*32 + q*8);
    #pragma unroll
    for (int mt=0; mt<8; ++mt){
      short8 ah = *(const short8*)(Ch + (mt*16 + l15)*128 + kc2*32 + q*8);
      short8 al = *(const short8*)(Cl + (mt*16 + l15)*128 + kc2*32 + q*8);
      #pragma unroll
      for (int nt=0; nt<4; ++nt){
        acc2[mt][nt] = __builtin_amdgcn_mfma_f32_16x16x32_bf16(ah, bk[nt], acc2[mt][nt], 0,0,0);
        acc2[mt][nt] = __builtin_amdgcn_mfma_f32_16x16x32_bf16(al, bk[nt], acc2[mt][nt], 0,0,0);
      }
    }
  }
  // phase 2 epilogue: s2p = sum_m kuf[m][b] * T[m][b]
  float s2p[4] = {0.f, 0.f, 0.f, 0.f};
  #pragma unroll
  for (int nt=0; nt<4; ++nt){
    const int bl = wn2 + nt*16 + l15;
    #pragma unroll
    for (int mt=0; mt<8; ++mt){
      const int m0 = mt*16 + q*4;
      uint2 pk = *(const uint2*)(kufT + (size_t)bl*136 + m0);
      f32x4 t = acc2[mt][nt];
      s2p[nt] += bf2f((unsigned short)(pk.x & 0xffff)) * t[0]
               + bf2f((unsigned short)(pk.x >> 16))    * t[1]
               + bf2f((unsigned short)(pk.y & 0xffff)) * t[2]
               + bf2f((unsigned short)(pk.y >> 16))    * t[3];
    }
  }
  #pragma unroll
  for (int nt=0; nt<4; ++nt){
    mu[nt]  += __shfl_xor(mu[nt], 16);  mu[nt]  += __shfl_xor(mu[nt], 32);
    s2p[nt] += __shfl_xor(s2p[nt], 16); s2p[nt] += __shfl_xor(s2p[nt], 32);
  }
  if (lane < 16){
    #pragma unroll
    for (int nt=0; nt<4; ++nt){
      size_t col = (size_t)ho*B_ + bblk*256 + wn2 + nt*16 + lane;
      stout(out, col,                  mu[nt],        isbf);
      stout(out, (size_t)HO*B_ + col,  s2 - s2p[nt],  isbf);
    }
  }
}

// ---------------- launch ----------------
extern "C" void kernel_launch(void* const* d_in, const int* in_sizes, int n_in,
                              void* d_out, int out_size, void* d_ws, size_t ws_size,
                              hipStream_t stream) {
  const void* x      = d_in[0];
  const void* z      = d_in[1];
  const void* u_mean = d_in[2];
  const void* u_tril = d_in[3];
  const void* theta  = d_in[4];
  char* ws = (char*)d_ws;

  int*   flag   = (int*)(ws + OFF_FLAG);
  float* inv_ls = (float*)(ws + OFF_INVLS);
  float* sf2    = (float*)(ws + OFF_SF2);
  float* zn2    = (float*)(ws + OFF_ZN2);
  float* xn2    = (float*)(ws + OFF_XN2);
  float* wv     = (float*)(ws + OFF_W);
  unsigned short* zsw = (unsigned short*)(ws + OFF_ZS);
  unsigned short* xsw = (unsigned short*)(ws + OFF_XS);
  unsigned short* Chi = (unsigned short*)(ws + OFF_CHI);
  unsigned short* Clo = (unsigned short*)(ws + OFF_CLO);

  k_hypers<<<1, 256, 0, stream>>>(theta, x, flag, inv_ls, sf2);
  k_scale<<<dim3(2048), 256, 0, stream>>>(x, z, flag, inv_ls, xsw, zsw, xn2, zn2);
  k_fact<<<64, 512, 156672, stream>>>(zsw, zn2, sf2, u_mean, u_tril, flag, wv, Chi, Clo);
  k_main<<<dim3(16, 64), 256, 69632 + 2048, stream>>>(zsw, xsw, zn2, xn2, wv, Chi, Clo, sf2, flag, (void*)d_out);
}

// Round 9
// 225.738 us; speedup vs baseline: 1.0752x; 1.0178x over previous
//
#include <hip/hip_runtime.h>
#include <cstdint>
#include <cstddef>

// ---------------- constants ----------------
constexpr int B_   = 4096;
constexpr int DIN  = 256;
constexpr int OUT_ = 32;
constexpr int MM   = 128;
constexpr int NH_  = 2;
constexpr int HO   = 64;          // NH*OUT
constexpr int TRIL = 8256;        // 128*129/2
constexpr float JIT = 1e-4f;

// ---------------- workspace layout ----------------
constexpr size_t al4k(size_t x){ return (x + 4095) & ~size_t(4095); }
constexpr size_t OFF_FLAG  = 0;                               // int
constexpr size_t OFF_INVLS = 4096;                            // f32 [2][256]
constexpr size_t OFF_SF2   = al4k(OFF_INVLS + 2*256*4);       // f32 [2]
constexpr size_t OFF_ZN2   = al4k(OFF_SF2 + 64);              // f32 [2][4096]
constexpr size_t OFF_XN2   = al4k(OFF_ZN2 + 8192*4);          // f32 [2][4096]
constexpr size_t OFF_W     = al4k(OFF_XN2 + 8192*4);          // f32 [64][128]
constexpr size_t OFF_ZS    = al4k(OFF_W + 8192*4);            // bf16 [2][4096][256]
constexpr size_t OFF_XS    = al4k(OFF_ZS + (size_t)2097152*2);
constexpr size_t OFF_VTH   = al4k(OFF_XS + (size_t)2097152*2); // (unused after merge)
constexpr size_t OFF_VTL   = al4k(OFF_VTH + (size_t)1048576*2);
constexpr size_t OFF_CHI   = al4k(OFF_VTL + (size_t)1048576*2);// bf16 [64][128][128]
constexpr size_t OFF_CLO   = al4k(OFF_CHI + (size_t)1048576*2);

typedef float f32x4 __attribute__((ext_vector_type(4)));
typedef short short8 __attribute__((ext_vector_type(8)));

__device__ __forceinline__ float bf2f(unsigned short u){
  union{unsigned int i; float f;} v; v.i = ((unsigned)u) << 16; return v.f;
}
__device__ __forceinline__ unsigned short f2bf(float f){
  union{float f; unsigned int i;} v; v.f = f;
  unsigned int r = v.i + 0x7fffu + ((v.i >> 16) & 1u);
  return (unsigned short)(r >> 16);
}
__device__ __forceinline__ float ldin(const void* p, size_t i, int isbf){
  if (isbf) return bf2f(((const unsigned short*)p)[i]);
  return ((const float*)p)[i];
}
__device__ __forceinline__ void stout(void* p, size_t i, float v, int isbf){
  if (isbf) ((unsigned short*)p)[i] = f2bf(v);
  else ((float*)p)[i] = v;
}
// async global->LDS, 16B per lane; LDS dest = wave-uniform base + lane*16
__device__ __forceinline__ void gl_lds16(const unsigned short* g, unsigned short* l){
  __builtin_amdgcn_global_load_lds(
      (const __attribute__((address_space(1))) unsigned int*)g,
      (__attribute__((address_space(3))) unsigned int*)l, 16, 0, 0);
}

// ---------------- K1: detect dtype + hypers (merged) ----------------
__global__ void k_hypers(const void* __restrict__ theta, const void* __restrict__ x,
                         int* __restrict__ flagp,
                         float* __restrict__ inv_ls, float* __restrict__ sf2){
  __shared__ int sflag;
  int t = threadIdx.x;
  if (t < 64){
    unsigned int w0 = ((const unsigned int*)theta)[t];
    unsigned int w1 = ((const unsigned int*)x)[t];
    float a0 = fabsf(bf2f((unsigned short)(w0 & 0xffffu)));
    float a1 = fabsf(bf2f((unsigned short)(w1 & 0xffffu)));
    int c = ((a0 > 9.3e-10f && a0 < 64.f) ? 1 : 0) + ((a1 > 9.3e-10f && a1 < 64.f) ? 1 : 0);
    c += __shfl_down(c, 32); c += __shfl_down(c, 16); c += __shfl_down(c, 8);
    c += __shfl_down(c, 4);  c += __shfl_down(c, 2);  c += __shfl_down(c, 1);
    if (t == 0){ sflag = (c >= 64) ? 1 : 0; *flagp = sflag; }
  }
  __syncthreads();
  const int isbf = sflag;
  for (int i = t; i < NH_*257; i += blockDim.x){
    int h = i / 257, j = i - h*257;
    float v = ldin(theta, i, isbf);
    if (j == 0) sf2[h] = __expf(v);
    else inv_ls[h*DIN + j - 1] = __expf(-v);
  }
}

// ---------------- K2: scale x and z by 1/ls -> bf16 + squared norms --------
__global__ void k_scale(const void* __restrict__ xsrc, const void* __restrict__ zsrc,
                        const int* flagp, const float* __restrict__ inv_ls,
                        unsigned short* __restrict__ xdst, unsigned short* __restrict__ zdst,
                        float* __restrict__ xn2, float* __restrict__ zn2){
  const int isbf = *flagp;
  const int wave = threadIdx.x >> 6, lane = threadIdx.x & 63;
  int bx = blockIdx.x;
  const void* src; unsigned short* dst; float* n2; int r;
  if (bx < 1024){ src = xsrc; dst = xdst; n2 = xn2; r = bx*4 + wave; }
  else          { src = zsrc; dst = zdst; n2 = zn2; r = (bx-1024)*4 + wave; }
  const int d0 = lane*4;
  float v[4];
  if (isbf){
    uint2 uu = *(const uint2*)((const unsigned short*)src + (size_t)r*DIN + d0);
    v[0]=bf2f((unsigned short)(uu.x & 0xffffu)); v[1]=bf2f((unsigned short)(uu.x >> 16));
    v[2]=bf2f((unsigned short)(uu.y & 0xffffu)); v[3]=bf2f((unsigned short)(uu.y >> 16));
  } else {
    f32x4 f = *(const f32x4*)((const float*)src + (size_t)r*DIN + d0);
    v[0]=f[0]; v[1]=f[1]; v[2]=f[2]; v[3]=f[3];
  }
  #pragma unroll
  for (int h = 0; h < 2; ++h){
    f32x4 il = *(const f32x4*)(inv_ls + h*DIN + d0);
    unsigned short rb[4];
    float p = 0.f;
    #pragma unroll
    for (int k = 0; k < 4; ++k){
      float s = v[k] * il[k];
      rb[k] = f2bf(s);
      float qv = bf2f(rb[k]);
      p += qv*qv;
    }
    uint2 pk;
    pk.x = (unsigned)rb[0] | ((unsigned)rb[1] << 16);
    pk.y = (unsigned)rb[2] | ((unsigned)rb[3] << 16);
    *(uint2*)(dst + ((size_t)h*4096 + r)*DIN + d0) = pk;
    p += __shfl_xor(p, 32); p += __shfl_xor(p, 16); p += __shfl_xor(p, 8);
    p += __shfl_xor(p, 4);  p += __shfl_xor(p, 2);  p += __shfl_xor(p, 1);
    if (lane == 0) n2[(size_t)h*4096 + r] = p;
  }
}

// ---------------- K3: FUSED kuu + Cholesky + trtri + Q/w/P/C (one kernel) ----------
// 512 threads / 8 waves. LDS regions (153 KB total):
//   A [0..82432):      float T tiles (80.5KB) + zn2l; kuu staging zsl aliases T[0..8KB);
//                      later aliased by Sth/Stl
//   B [82432..152064): VT bf16 hi/lo [128][136]x2; later aliased by Qh/Ql then Ph/Pl
//   floats [152064..): ul[128], wpart[8][128]
// Round-6 configuration exactly (226.5 µs total, k_fact 100.7 µs stable under
// rocprof). Lookahead Cholesky (r7: -13µs wall) and kuu counted-vmcnt pipeline
// (r8: -3µs wall; also distorts rocprof by +35µs) both reverted.
constexpr int TLD = 20;          // tile leading dim (floats)
constexpr int TSZ = 16*TLD;      // 320 floats per tile
__device__ __forceinline__ int tb(int bi, int bj){ return (bi*(bi+1)/2 + bj)*TSZ; }
__device__ __forceinline__ int vb(int bi, int bj){ return (36 + bi*(bi-1)/2 + bj)*TSZ; }
__device__ __forceinline__ int tri_bi(int t){
  int bi = (int)((sqrtf(8.f*t + 1.f) - 1.f) * 0.5f);
  while ((bi+1)*(bi+2)/2 <= t) ++bi;
  while (bi*(bi+1)/2 > t) --bi;
  return bi;
}

__global__ __launch_bounds__(512) void k_fact(
    const unsigned short* __restrict__ zs, const float* __restrict__ zn2,
    const float* __restrict__ sf2,
    const void* __restrict__ u_mean, const void* __restrict__ u_tril,
    const int* flagp, float* __restrict__ wg,
    unsigned short* __restrict__ Chi, unsigned short* __restrict__ Clo){
  const int ho = blockIdx.x, h = ho >> 5, o = ho & 31;
  const int tid = threadIdx.x;
  const int lane = tid & 63, wid = tid >> 6;      // 8 waves
  const int l15 = lane & 15, q = lane >> 4;
  const int wn = wid * 16;                        // 16 output-cols per wave
  const int isbf = *flagp;
  extern __shared__ char smem[];
  float* T = (float*)smem;                            // 64 tiles
  float* zn2l = T + 64*TSZ;                           // [128] @81920
  unsigned short* zsl = (unsigned short*)T;           // kuu staging alias [128][32]
  unsigned short* VTh = (unsigned short*)(smem + 82432);   // [128][136]
  unsigned short* VTl = (unsigned short*)(smem + 117248);  // [128][136]
  unsigned short* Sth = (unsigned short*)smem;             // alias A (post-trtri)
  unsigned short* Stl = (unsigned short*)(smem + 34816);
  unsigned short* Qh = VTh;                                // alias B (post-Q-phase)
  unsigned short* Ql = VTl;
  float* ul    = (float*)(smem + 152064);             // [128]
  float* wpart = (float*)(smem + 152576);             // [8][128]

  if (tid < 128){
    zn2l[tid] = zn2[ho*128 + tid];
    ul[tid]   = ldin(u_mean, (size_t)o*128 + tid, isbf);
  }
  const size_t zbase = (size_t)ho * 32768;
  const int sw = ((q ^ ((l15 >> 1) & 3)) << 3);
  const int rA = wn + (lane >> 2);
  const int sg = ((lane & 3) ^ ((rA >> 1) & 3)) << 3;
  const f32x4 z4 = {0.f,0.f,0.f,0.f};
  // ---- phase kuu: zs zs^T via MFMA ----
  f32x4 acck[8];
  #pragma unroll
  for (int mt=0; mt<8; ++mt) acck[mt]=z4;
  for (int kc = 0; kc < 8; ++kc){
    __syncthreads();
    gl_lds16(zs + zbase + (size_t)rA*256 + kc*32 + sg, zsl + wn*32);
    __syncthreads();
    short8 b0 = *(const short8*)(zsl + (wn + l15)*32 + sw);
    #pragma unroll
    for (int mt=0; mt<8; ++mt){
      short8 a = *(const short8*)(zsl + (mt*16 + l15)*32 + sw);
      acck[mt] = __builtin_amdgcn_mfma_f32_16x16x32_bf16(a, b0, acck[mt], 0,0,0);
    }
  }
  __syncthreads();   // all zsl reads done before tiles (alias) are written
  // ---- epilogue: kuu -> T tiles (lower + full diag), + jitter ----
  const float s2v = sf2[h];
  {
    const int n = wn + l15;
    const float nn = zn2l[n];
    const int bn = wid;
    #pragma unroll
    for (int mt=0; mt<8; ++mt){
      #pragma unroll
      for (int r=0; r<4; ++r){
        int m = mt*16 + q*4 + r;
        float d2 = fmaxf(zn2l[m] + nn - 2.f*acck[mt][r], 0.f);
        float a = s2v * __expf(-0.5f*d2);
        if (m == n) a += JIT;
        int bm = m >> 4;
        if (bn <= bm) T[tb(bm, bn) + (m & 15)*TLD + (n & 15)] = a;
      }
    }
  }
  __syncthreads();
  // ---- blocked Cholesky, panel width 16 (sequential schedule) ----
  for (int kb = 0; kb < 8; ++kb){
    if (wid == 0){
      float* D = T + tb(kb, kb);
      const int r = lane & 15;
      const bool act = (lane < 16);
      float a[16];
      #pragma unroll
      for (int k = 0; k < 16; ++k) a[k] = 0.f;
      if (act){
        #pragma unroll
        for (int k2 = 0; k2 < 4; ++k2)
          *(f32x4*)(a + 4*k2) = *(const f32x4*)(D + r*TLD + 4*k2);
      }
      #pragma unroll
      for (int c = 0; c < 16; ++c){
        float pr[16];
        #pragma unroll
        for (int k = 0; k < 16; ++k) pr[k] = __shfl(a[k], c);
        float rsq = rsqrtf(pr[c]);
        if (act && r >= c) a[c] *= rsq;
        float lrc = a[c];
        #pragma unroll
        for (int k = 0; k < 16; ++k)
          if (k > c && act && r > c) a[k] -= lrc * (pr[k] * rsq);
      }
      float v[16];
      #pragma unroll
      for (int k = 0; k < 16; ++k) v[k] = 0.f;
      const int c = lane & 15;
      #pragma unroll
      for (int i = 0; i < 16; ++i){
        float lrow[16];
        #pragma unroll
        for (int k = 0; k < 16; ++k) lrow[k] = __shfl(a[k], i);
        float rli = 1.f / lrow[i];
        float s = 0.f;
        #pragma unroll
        for (int k = 0; k < 16; ++k)
          if (k < i) s += ((k >= c) ? lrow[k]*v[k] : 0.f);
        v[i] = (c == i) ? rli : ((c < i) ? -s*rli : 0.f);
      }
      if (act){
        #pragma unroll
        for (int i = 0; i < 16; ++i) D[i*TLD + c] = v[i];
      }
    }
    __syncthreads();
    {
      const int gi = kb*16 + 16 + tid;
      if (gi < 128){
        float* Bp = T + tb(gi >> 4, kb) + (gi & 15)*TLD;
        const float* Vd = T + tb(kb, kb);
        float b[16], nb[16];
        #pragma unroll
        for (int k2 = 0; k2 < 4; ++k2) *(f32x4*)(b + 4*k2) = *(const f32x4*)(Bp + 4*k2);
        #pragma unroll
        for (int j = 0; j < 16; ++j){
          float s = 0.f;
          #pragma unroll
          for (int k = 0; k < 16; ++k)
            if (k <= j) s += b[k] * Vd[j*TLD + k];
          nb[j] = s;
        }
        #pragma unroll
        for (int k2 = 0; k2 < 4; ++k2) *(f32x4*)(Bp + 4*k2) = *(const f32x4*)(nb + 4*k2);
      }
    }
    __syncthreads();
    {
      const int D8 = 7 - kb;
      const int Tn = D8*(D8+1)/2;
      const int r15 = lane & 15, c0 = (lane >> 4)*4;
      for (int tt = wid; tt < Tn; tt += 8){
        int bi1 = tri_bi(tt);
        int bj1 = tt - bi1*(bi1+1)/2;
        int bi = kb + 1 + bi1, bj = kb + 1 + bj1;
        const float* Lr = T + tb(bi, kb) + r15*TLD;
        const float* Lc = T + tb(bj, kb) + c0*TLD;
        float* Cp = T + tb(bi, bj) + r15*TLD + c0;
        float lr[16];
        #pragma unroll
        for (int k2 = 0; k2 < 4; ++k2) *(f32x4*)(lr + 4*k2) = *(const f32x4*)(Lr + 4*k2);
        f32x4 accv = *(const f32x4*)Cp;
        #pragma unroll
        for (int cc = 0; cc < 4; ++cc){
          float lc[16];
          #pragma unroll
          for (int k2 = 0; k2 < 4; ++k2) *(f32x4*)(lc + 4*k2) = *(const f32x4*)(Lc + cc*TLD + 4*k2);
          float s = 0.f;
          #pragma unroll
          for (int k = 0; k < 16; ++k) s += lr[k]*lc[k];
          accv[cc] -= s;
        }
        *(f32x4*)Cp = accv;
      }
    }
    __syncthreads();
  }
  // ---- trtri by anti-diagonal wavefronts ----
  {
    const int r15 = lane & 15, c0 = (lane >> 4)*4;
    for (int d = 1; d < 8; ++d){
      for (int tt = wid; tt < 8 - d; tt += 8){
        const int bi = d + tt, jb = bi - d;
        float W0=0.f, W1=0.f, W2=0.f, W3=0.f;
        for (int k = jb; k < bi; ++k){
          const float* Lt = T + tb(bi, k) + r15*TLD;
          const float* Vt = (k == jb) ? (T + tb(jb, jb)) : (T + vb(k, jb));
          float lr[16];
          #pragma unroll
          for (int k2 = 0; k2 < 4; ++k2) *(f32x4*)(lr + 4*k2) = *(const f32x4*)(Lt + 4*k2);
          #pragma unroll
          for (int kk = 0; kk < 16; ++kk){
            f32x4 vv = *(const f32x4*)(Vt + kk*TLD + c0);
            W0 += lr[kk]*vv[0]; W1 += lr[kk]*vv[1];
            W2 += lr[kk]*vv[2]; W3 += lr[kk]*vv[3];
          }
        }
        const float* Vd = T + tb(bi, bi) + r15*TLD;
        const int cgl = (lane >> 4);
        f32x4 Rr = {0.f,0.f,0.f,0.f};
        #pragma unroll
        for (int k = 0; k < 16; ++k){
          float vd = Vd[k];
          float w0 = __shfl(W0, (cgl<<4)|k);
          float w1 = __shfl(W1, (cgl<<4)|k);
          float w2 = __shfl(W2, (cgl<<4)|k);
          float w3 = __shfl(W3, (cgl<<4)|k);
          Rr[0] -= vd*w0; Rr[1] -= vd*w1; Rr[2] -= vd*w2; Rr[3] -= vd*w3;
        }
        *(f32x4*)(T + vb(bi, jb) + r15*TLD + c0) = Rr;
      }
      __syncthreads();
    }
  }
  // ---- convert V (T tiles) -> VT bf16 hi/lo in LDS region B: VT[c][r]=V[r][c] ----
  for (int e = tid; e < 16384; e += 512){
    int c = e >> 7, rr = e & 127;
    int bc = c >> 4, br = rr >> 4;
    float v = 0.f;
    if (br == bc)      v = T[tb(br, bc) + (rr & 15)*TLD + (c & 15)];
    else if (br > bc)  v = T[vb(br, bc) + (rr & 15)*TLD + (c & 15)];
    unsigned short hi = f2bf(v);
    VTh[c*136 + rr] = hi;
    VTl[c*136 + rr] = f2bf(v - bf2f(hi));
  }
  __syncthreads();   // VT complete (and all T reads done -> A free after this phase)
  // ---- phase Q: Q = VT * VT^T via hi/lo 3-pass MFMA, pure LDS reads ----
  f32x4 acc[8];
  #pragma unroll
  for (int mt=0; mt<8; ++mt) acc[mt]=z4;
  #pragma unroll
  for (int kc2 = 0; kc2 < 4; ++kc2){
    const int ko = kc2*32 + q*8;
    short8 b0h = *(const short8*)(VTh + (wn + l15)*136 + ko);
    short8 b0l = *(const short8*)(VTl + (wn + l15)*136 + ko);
    #pragma unroll
    for (int mt=0; mt<8; ++mt){
      short8 ah = *(const short8*)(VTh + (mt*16 + l15)*136 + ko);
      short8 al = *(const short8*)(VTl + (mt*16 + l15)*136 + ko);
      acc[mt] = __builtin_amdgcn_mfma_f32_16x16x32_bf16(ah, b0h, acc[mt], 0,0,0);
      acc[mt] = __builtin_amdgcn_mfma_f32_16x16x32_bf16(ah, b0l, acc[mt], 0,0,0);
      acc[mt] = __builtin_amdgcn_mfma_f32_16x16x32_bf16(al, b0h, acc[mt], 0,0,0);
    }
  }
  // ---- w = Q u (shuffle reduce over the wave's 16 cols) ----
  {
    float u0 = ul[wn + l15];
    float wpm[32];
    #pragma unroll
    for (int mt=0; mt<8; ++mt){
      #pragma unroll
      for (int r=0; r<4; ++r)
        wpm[mt*4+r] = acc[mt][r]*u0;
    }
    #pragma unroll
    for (int i = 0; i < 32; ++i){
      wpm[i] += __shfl_xor(wpm[i], 1);
      wpm[i] += __shfl_xor(wpm[i], 2);
      wpm[i] += __shfl_xor(wpm[i], 4);
      wpm[i] += __shfl_xor(wpm[i], 8);
    }
    if (l15 == 0){
      #pragma unroll
      for (int i = 0; i < 32; ++i){
        int m = (i>>2)*16 + q*4 + (i&3);
        wpart[wid*128 + m] = wpm[i];
      }
    }
  }
  __syncthreads();   // all Q-phase VT reads done (B free to overwrite) + wpart visible
  if (tid < 128){
    float s = 0.f;
    #pragma unroll
    for (int wv = 0; wv < 8; ++wv) s += wpart[wv*128 + tid];
    wg[ho*128 + tid] = s;
  }
  // ---- write Q dense bf16 hi/lo over VT (B); fill St = S^T over T (A) ----
  {
    const int n0 = wn + l15;
    #pragma unroll
    for (int mt=0; mt<8; ++mt){
      #pragma unroll
      for (int r=0; r<4; ++r){
        int m = mt*16 + q*4 + r;
        float v0 = acc[mt][r];
        unsigned short h0 = f2bf(v0);
        Qh[m*136 + n0] = h0; Ql[m*136 + n0] = f2bf(v0 - bf2f(h0));
      }
    }
  }
  for (int e = tid; e < 16384; e += 512){
    int k = e >> 7, j = e & 127;
    float val = 0.f;
    if (j <= k) val = ldin(u_tril, (size_t)o*TRIL + (size_t)k*(k+1)/2 + j, isbf);
    unsigned short hi = f2bf(val);
    Sth[j*136 + k] = hi;
    Stl[j*136 + k] = f2bf(val - bf2f(hi));
  }
  __syncthreads();   // Qh/Ql + Sth/Stl visible
  // ---- phase P: P = Q*S via MFMA, 3 passes ----
  f32x4 acc3[8];
  #pragma unroll
  for (int mt=0; mt<8; ++mt) acc3[mt]=z4;
  #pragma unroll
  for (int kc2 = 0; kc2 < 4; ++kc2){
    const int ko = kc2*32 + q*8;
    short8 b0h = *(const short8*)(Sth + (wn + l15)*136 + ko);
    short8 b0l = *(const short8*)(Stl + (wn + l15)*136 + ko);
    #pragma unroll
    for (int mt=0; mt<8; ++mt){
      short8 ah = *(const short8*)(Qh + (mt*16 + l15)*136 + ko);
      short8 al = *(const short8*)(Ql + (mt*16 + l15)*136 + ko);
      acc3[mt] = __builtin_amdgcn_mfma_f32_16x16x32_bf16(ah, b0h, acc3[mt], 0,0,0);
      acc3[mt] = __builtin_amdgcn_mfma_f32_16x16x32_bf16(al, b0h, acc3[mt], 0,0,0);
      acc3[mt] = __builtin_amdgcn_mfma_f32_16x16x32_bf16(ah, b0l, acc3[mt], 0,0,0);
    }
  }
  __syncthreads();   // all Qh/Ql reads done before overwrite with Ph/Pl
  // ---- write P dense bf16 hi/lo over Qh/Ql ----
  {
    const int n0 = wn + l15;
    #pragma unroll
    for (int mt=0; mt<8; ++mt){
      #pragma unroll
      for (int r=0; r<4; ++r){
        int m = mt*16 + q*4 + r;
        float v0 = acc3[mt][r];
        unsigned short h0 = f2bf(v0);
        Qh[m*136 + n0] = h0; Ql[m*136 + n0] = f2bf(v0 - bf2f(h0));
      }
    }
  }
  __syncthreads();
  // ---- phase PP^T: self cross-product, hi/lo 3-pass MFMA ----
  f32x4 acc2[8];
  #pragma unroll
  for (int mt=0; mt<8; ++mt) acc2[mt]=z4;
  #pragma unroll
  for (int kc2 = 0; kc2 < 4; ++kc2){
    const int ko = kc2*32 + q*8;
    short8 b0h = *(const short8*)(Qh + (wn + l15)*136 + ko);
    short8 b0l = *(const short8*)(Ql + (wn + l15)*136 + ko);
    #pragma unroll
    for (int mt=0; mt<8; ++mt){
      short8 ah = *(const short8*)(Qh + (mt*16 + l15)*136 + ko);
      short8 al = *(const short8*)(Ql + (mt*16 + l15)*136 + ko);
      acc2[mt] = __builtin_amdgcn_mfma_f32_16x16x32_bf16(ah, b0h, acc2[mt], 0,0,0);
      acc2[mt] = __builtin_amdgcn_mfma_f32_16x16x32_bf16(ah, b0l, acc2[mt], 0,0,0);
      acc2[mt] = __builtin_amdgcn_mfma_f32_16x16x32_bf16(al, b0h, acc2[mt], 0,0,0);
    }
  }
  // ---- C epilogue: C = Q(regs) - PP^T -> bf16 hi/lo global ----
  {
    const size_t vbase = (size_t)ho * 16384;
    const int n = wn + l15;
    #pragma unroll
    for (int mt=0; mt<8; ++mt){
      #pragma unroll
      for (int r=0; r<4; ++r){
        int m = mt*16 + q*4 + r;
        float c = acc[mt][r] - acc2[mt][r];
        unsigned short hi = f2bf(c);
        unsigned short lo = f2bf(c - bf2f(hi));
        Chi[vbase + m*128 + n] = hi;
        Clo[vbase + m*128 + n] = lo;
      }
    }
  }
}

// ---------------- K9: fused main — kuf + mu + quadratic-form var -------------------
// BN=256: each block handles 256 x-cols (grid 16x64). B-operand in registers
// (double-buffered); only z staged via 3-buffer gl_lds + counted vmcnt.
__global__ __launch_bounds__(256, 2) void k_main(
    const unsigned short* __restrict__ zs, const unsigned short* __restrict__ xs,
    const float* __restrict__ zn2, const float* __restrict__ xn2,
    const float* __restrict__ wg, const unsigned short* __restrict__ Chi,
    const unsigned short* __restrict__ Clo, const float* __restrict__ sf2,
    const int* flagp, void* __restrict__ out){
  const int bblk = blockIdx.x, ho = blockIdx.y, h = ho >> 5;
  const int tid = threadIdx.x;
  const int lane = tid & 63, l15 = lane & 15, q = lane >> 4;
  const int wid = tid >> 6;
  const int wn = wid * 32;        // z-staging row split
  const int wn2 = wid * 64;       // output-column split (BN=256 / 4 waves)
  const int isbf = *flagp;
  extern __shared__ char smem[];
  unsigned short* zb0 = (unsigned short*)smem;          // [128][32] (8 KB each)
  unsigned short* zb1 = zb0 + 4096;
  unsigned short* zb2 = zb0 + 8192;
  unsigned short* kufT = (unsigned short*)smem;         // [256][136] (phase 2, aliases)
  float* zn2l = (float*)(smem + 69632);                 // [128]
  float* xn2l = zn2l + 128;                             // [256]
  float* wl   = xn2l + 256;                             // [128]

  if (tid < 128){
    zn2l[tid] = zn2[ho*128 + tid];
    wl[tid]   = wg[ho*128 + tid];
  }
  xn2l[tid] = xn2[(size_t)h*B_ + bblk*256 + tid];
  const size_t zbase = (size_t)ho * 32768;
  const size_t xbase = ((size_t)h*B_ + bblk*256) * 256;
  const int sw = ((q ^ ((l15 >> 1) & 3)) << 3);
  const int rA = wn + (lane >> 2);
  const int sg = ((lane & 3) ^ ((rA >> 1) & 3)) << 3;   // also valid for rA+16
  const f32x4 z4 = {0.f,0.f,0.f,0.f};
  f32x4 acc[8][4];
  #pragma unroll
  for (int mt=0; mt<8; ++mt){
    #pragma unroll
    for (int nt=0; nt<4; ++nt) acc[mt][nt]=z4;
  }
  unsigned short* zbp[3] = { zb0, zb1, zb2 };

  auto STAGEZ = [&](int c, unsigned short* zd){
    const int off = c*32;
    gl_lds16(zs + zbase + (size_t)rA*256      + off + sg, zd + wn*32);
    gl_lds16(zs + zbase + (size_t)(rA+16)*256 + off + sg, zd + (wn+16)*32);
  };
  auto LDB = [&](int c, short8* bd){
    #pragma unroll
    for (int nt=0; nt<4; ++nt)
      bd[nt] = *(const short8*)(xs + xbase + (size_t)(wn2 + nt*16 + l15)*256 + c*32 + q*8);
  };

  short8 bA[4], bB[4];
  STAGEZ(0, zb0);
  STAGEZ(1, zb1);
  LDB(0, bA);

  #pragma unroll
  for (int kc = 0; kc < 8; ++kc){
    unsigned short* zc = zbp[kc % 3];
    if (kc + 2 < 8) STAGEZ(kc + 2, zbp[(kc + 2) % 3]);
    if (kc + 1 < 8){ if (kc & 1) LDB(kc + 1, bA); else LDB(kc + 1, bB); }
    if (kc < 6)       asm volatile("s_waitcnt vmcnt(6)" ::: "memory");
    else if (kc == 6) asm volatile("s_waitcnt vmcnt(4)" ::: "memory");
    else              asm volatile("s_waitcnt vmcnt(0)" ::: "memory");
    __builtin_amdgcn_s_barrier();           // all waves' z chunk-kc landed
    __builtin_amdgcn_sched_barrier(0);
    const short8* bc = (kc & 1) ? bB : bA;
    #pragma unroll
    for (int mt=0; mt<8; ++mt){
      short8 a = *(const short8*)(zc + (mt*16 + l15)*32 + sw);
      #pragma unroll
      for (int nt=0; nt<4; ++nt)
        acc[mt][nt] = __builtin_amdgcn_mfma_f32_16x16x32_bf16(a, bc[nt], acc[mt][nt], 0,0,0);
    }
    asm volatile("s_waitcnt lgkmcnt(0)" ::: "memory");  // own ds_reads complete
    __builtin_amdgcn_sched_barrier(0);
    __builtin_amdgcn_s_barrier();           // all waves done reading buf[kc%3]
  }
  // phase 1 epilogue: kuf = sf2*exp(-0.5*d2); mu partial; store bf16 kufT
  const float s2 = sf2[h];
  float mu[4] = {0.f, 0.f, 0.f, 0.f};
  #pragma unroll
  for (int nt=0; nt<4; ++nt){
    const int bl = wn2 + nt*16 + l15;
    const float xn = xn2l[bl];
    #pragma unroll
    for (int mt=0; mt<8; ++mt){
      const int m0 = mt*16 + q*4;
      float kf[4];
      #pragma unroll
      for (int r=0; r<4; ++r){
        float d2 = fmaxf(zn2l[m0+r] + xn - 2.f*acc[mt][nt][r], 0.f);
        kf[r] = s2 * __expf(-0.5f*d2);
        mu[nt] += wl[m0+r] * kf[r];
      }
      uint2 pk;
      pk.x = (unsigned)f2bf(kf[0]) | ((unsigned)f2bf(kf[1]) << 16);
      pk.y = (unsigned)f2bf(kf[2]) | ((unsigned)f2bf(kf[3]) << 16);
      *(uint2*)(kufT + (size_t)bl*136 + m0) = pk;
    }
  }
  __syncthreads();
  // phase 2: T = (Chi + Clo) @ kuf   (K=128, 4 chunks of 32)
  f32x4 acc2[8][4];
  #pragma unroll
  for (int mt=0; mt<8; ++mt){
    #pragma unroll
    for (int nt=0; nt<4; ++nt) acc2[mt][nt]=z4;
  }
  const unsigned short* Ch = Chi + (size_t)ho*16384;
  const unsigned short* Cl = Clo + (size_t)ho*16384;
  #pragma unroll
  for (int kc2 = 0; kc2 < 4; ++kc2){
    short8 bk[4];
    #pragma unroll
    for (int nt=0; nt<4; ++nt)
      bk[nt] = *(const short8*)(kufT + (wn2 + nt*16 + l15)*136 + kc2*32 + q*8);
    #pragma unroll
    for (int mt=0; mt<8; ++mt){
      short8 ah = *(const short8*)(Ch + (mt*16 + l15)*128 + kc2*32 + q*8);
      short8 al = *(const short8*)(Cl + (mt*16 + l15)*128 + kc2*32 + q*8);
      #pragma unroll
      for (int nt=0; nt<4; ++nt){
        acc2[mt][nt] = __builtin_amdgcn_mfma_f32_16x16x32_bf16(ah, bk[nt], acc2[mt][nt], 0,0,0);
        acc2[mt][nt] = __builtin_amdgcn_mfma_f32_16x16x32_bf16(al, bk[nt], acc2[mt][nt], 0,0,0);
      }
    }
  }
  // phase 2 epilogue: s2p = sum_m kuf[m][b] * T[m][b]
  float s2p[4] = {0.f, 0.f, 0.f, 0.f};
  #pragma unroll
  for (int nt=0; nt<4; ++nt){
    const int bl = wn2 + nt*16 + l15;
    #pragma unroll
    for (int mt=0; mt<8; ++mt){
      const int m0 = mt*16 + q*4;
      uint2 pk = *(const uint2*)(kufT + (size_t)bl*136 + m0);
      f32x4 t = acc2[mt][nt];
      s2p[nt] += bf2f((unsigned short)(pk.x & 0xffff)) * t[0]
               + bf2f((unsigned short)(pk.x >> 16))    * t[1]
               + bf2f((unsigned short)(pk.y & 0xffff)) * t[2]
               + bf2f((unsigned short)(pk.y >> 16))    * t[3];
    }
  }
  #pragma unroll
  for (int nt=0; nt<4; ++nt){
    mu[nt]  += __shfl_xor(mu[nt], 16);  mu[nt]  += __shfl_xor(mu[nt], 32);
    s2p[nt] += __shfl_xor(s2p[nt], 16); s2p[nt] += __shfl_xor(s2p[nt], 32);
  }
  if (lane < 16){
    #pragma unroll
    for (int nt=0; nt<4; ++nt){
      size_t col = (size_t)ho*B_ + bblk*256 + wn2 + nt*16 + lane;
      stout(out, col,                  mu[nt],        isbf);
      stout(out, (size_t)HO*B_ + col,  s2 - s2p[nt],  isbf);
    }
  }
}

// ---------------- launch ----------------
extern "C" void kernel_launch(void* const* d_in, const int* in_sizes, int n_in,
                              void* d_out, int out_size, void* d_ws, size_t ws_size,
                              hipStream_t stream) {
  const void* x      = d_in[0];
  const void* z      = d_in[1];
  const void* u_mean = d_in[2];
  const void* u_tril = d_in[3];
  const void* theta  = d_in[4];
  char* ws = (char*)d_ws;

  int*   flag   = (int*)(ws + OFF_FLAG);
  float* inv_ls = (float*)(ws + OFF_INVLS);
  float* sf2    = (float*)(ws + OFF_SF2);
  float* zn2    = (float*)(ws + OFF_ZN2);
  float* xn2    = (float*)(ws + OFF_XN2);
  float* wv     = (float*)(ws + OFF_W);
  unsigned short* zsw = (unsigned short*)(ws + OFF_ZS);
  unsigned short* xsw = (unsigned short*)(ws + OFF_XS);
  unsigned short* Chi = (unsigned short*)(ws + OFF_CHI);
  unsigned short* Clo = (unsigned short*)(ws + OFF_CLO);

  k_hypers<<<1, 256, 0, stream>>>(theta, x, flag, inv_ls, sf2);
  k_scale<<<dim3(2048), 256, 0, stream>>>(x, z, flag, inv_ls, xsw, zsw, xn2, zn2);
  k_fact<<<64, 512, 156672, stream>>>(zsw, zn2, sf2, u_mean, u_tril, flag, wv, Chi, Clo);
  k_main<<<dim3(16, 64), 256, 69632 + 2048, stream>>>(zsw, xsw, zn2, xn2, wv, Chi, Clo, sf2, flag, (void*)d_out);
}